// Round 6
// baseline (639.375 us; speedup 1.0000x reference)
//
#include <hip/hip_runtime.h>

#define NN 100000      // nodes
#define NE 1600000     // edges
#define NF 128         // input features
#define H  64          // hidden channels
#define NG 4096        // graphs
#define SCAN_B 512
#define NB ((NN + SCAN_B - 1) / SCAN_B)   // 196 scan blocks

typedef unsigned long long u64;

// ---------------- degree histogram (int) ----------------
__global__ __launch_bounds__(256) void k_hist(const int* __restrict__ dst,
                                              int* __restrict__ cnt) {
  int e = blockIdx.x * blockDim.x + threadIdx.x;
  if (e < NE) atomicAdd(&cnt[dst[e]], 1);
}

__global__ __launch_bounds__(256) void k_dinv(const int* __restrict__ cnt,
                                              float* __restrict__ dinv) {
  int i = blockIdx.x * blockDim.x + threadIdx.x;
  if (i < NN) dinv[i] = 1.0f / sqrtf((float)cnt[i] + 1.0f);
}

// ---------------- 3-phase exclusive scan of cnt -> row_ptr ----------------
__global__ __launch_bounds__(SCAN_B) void k_scan_a(const int* __restrict__ cnt,
                                                   int* __restrict__ incl,
                                                   int* __restrict__ bsum) {
  __shared__ int sh[SCAN_B];
  const int i = blockIdx.x * SCAN_B + threadIdx.x;
  int v = (i < NN) ? cnt[i] : 0;
  sh[threadIdx.x] = v;
  __syncthreads();
  for (int off = 1; off < SCAN_B; off <<= 1) {
    int add = (threadIdx.x >= off) ? sh[threadIdx.x - off] : 0;
    __syncthreads();
    sh[threadIdx.x] += add;
    __syncthreads();
  }
  if (i < NN) incl[i] = sh[threadIdx.x];
  if (threadIdx.x == SCAN_B - 1) bsum[blockIdx.x] = sh[SCAN_B - 1];
}

__global__ __launch_bounds__(256) void k_scan_b(int* __restrict__ bsum,
                                                int* __restrict__ boff) {
  __shared__ int sh[256];
  const int t = threadIdx.x;
  int v = (t < NB) ? bsum[t] : 0;
  sh[t] = v;
  __syncthreads();
  for (int off = 1; off < 256; off <<= 1) {
    int add = (t >= off) ? sh[t - off] : 0;
    __syncthreads();
    sh[t] += add;
    __syncthreads();
  }
  if (t < NB) boff[t] = sh[t] - v;  // exclusive
}

__global__ __launch_bounds__(SCAN_B) void k_scan_c(const int* __restrict__ cnt,
                                                   const int* __restrict__ incl,
                                                   const int* __restrict__ boff,
                                                   int* __restrict__ row_ptr,
                                                   int* __restrict__ cursor) {
  const int i = blockIdx.x * SCAN_B + threadIdx.x;
  if (i < NN) {
    const int start = incl[i] + boff[blockIdx.x] - cnt[i];
    row_ptr[i] = start;
    cursor[i] = start;
  }
  if (i == 0) row_ptr[NN] = NE;
}

// ---------------- CSR fill: packed (src, coef) per slot ----------------
__global__ __launch_bounds__(256) void k_fill(const int* __restrict__ src,
                                              const int* __restrict__ dst,
                                              const float* __restrict__ dinv,
                                              int* __restrict__ cursor,
                                              float2* __restrict__ csr) {
  int e = blockIdx.x * blockDim.x + threadIdx.x;
  if (e < NE) {
    const int s = src[e], d = dst[e];
    const int pos = atomicAdd(&cursor[d], 1);
    csr[pos] = make_float2(__int_as_float(s), dinv[s] * dinv[d]);
  }
}

// ---- node GEMM, lane=row, FULL-ROW ownership (race-free in-place) --------
// Block = 128 threads = 128 rows/tile. Each thread owns one row and ALL 64
// output cols: 64 conv accumulators (+64 skip accumulators if SK) in VGPRs.
// Weights transposed in LDS, read at wave-uniform addresses (broadcast b128).
// SK: outS may alias `in` -- each thread reads ONLY its own row, and all its
// loads precede its stores; no other thread reads or writes that row.
template <int CI, bool SK>
__global__ __launch_bounds__(128) void k_gemm(const float* in,
                                              const float* __restrict__ W,
                                              const float* __restrict__ Ws,
                                              const float* __restrict__ bs,
                                              float* __restrict__ out,
                                              float* outS) {
  __shared__ float wt[(SK ? 2 : 1) * 64 * CI];  // wt[c][k] ; then wst[c][k]
  for (int i = threadIdx.x; i < CI * 64; i += 128) {
    const int k = i >> 6, c = i & 63;
    wt[c * CI + k] = W[i];
    if (SK) wt[64 * CI + c * CI + k] = Ws[i];
  }
  __syncthreads();
  const int lane = threadIdx.x & 63;
  const int wv   = threadIdx.x >> 6;  // 0..1
  const int NT = (NN + 127) / 128;    // 782 row-tiles
  for (int t = blockIdx.x; t < NT; t += gridDim.x) {
    const int row  = t * 128 + wv * 64 + lane;
    const int rowc = min(row, NN - 1);
    const float* rp = in + (size_t)rowc * CI;
    float acc[64];
    float sacc[SK ? 64 : 1];
#pragma unroll
    for (int c = 0; c < 64; ++c) acc[c] = 0.0f;
    if (SK) {
#pragma unroll
      for (int c = 0; c < 64; ++c) sacc[c] = bs[c];
    }
#pragma unroll 2
    for (int k4 = 0; k4 < CI; k4 += 4) {
      const float4 r = *(const float4*)(rp + k4);
#pragma unroll
      for (int c = 0; c < 64; ++c) {
        const float4 w = *(const float4*)&wt[c * CI + k4];
        acc[c] = fmaf(r.x, w.x, acc[c]);
        acc[c] = fmaf(r.y, w.y, acc[c]);
        acc[c] = fmaf(r.z, w.z, acc[c]);
        acc[c] = fmaf(r.w, w.w, acc[c]);
        if (SK) {
          const float4 s = *(const float4*)&wt[64 * CI + c * CI + k4];
          sacc[c] = fmaf(r.x, s.x, sacc[c]);
          sacc[c] = fmaf(r.y, s.y, sacc[c]);
          sacc[c] = fmaf(r.z, s.z, sacc[c]);
          sacc[c] = fmaf(r.w, s.w, sacc[c]);
        }
      }
    }
    if (row < NN) {
      float* op = out + (size_t)row * 64;
#pragma unroll
      for (int c = 0; c < 64; c += 4)
        *(float4*)(op + c) = make_float4(acc[c], acc[c + 1], acc[c + 2], acc[c + 3]);
      if (SK) {
        float* sp = outS + (size_t)row * 64;
#pragma unroll
        for (int c = 0; c < 64; c += 4)
          *(float4*)(sp + c) =
              make_float4(sacc[c], sacc[c + 1], sacc[c + 2], sacc[c + 3]);
      }
    }
  }
}

// ------- CSR aggregation + finalize: h = relu(agg + hw*di^2 + bias) [+ hs] ---
// 16 independent row-gathers in flight; csr streamed nontemporal.
// ADD_S path runs with hs == h (read then write same addr, same thread).
template <bool ADD_S>
__global__ __launch_bounds__(256) void k_agg(const float* __restrict__ hw,
                                             const float* hs,
                                             const u64* __restrict__ csr,
                                             const int* __restrict__ row_ptr,
                                             const float* __restrict__ dinv,
                                             const float* __restrict__ bias,
                                             float* h) {
  const int col = threadIdx.x & 63;
  const int wv  = threadIdx.x >> 6;
  const float brc = bias[col];
  for (int n = blockIdx.x * 4 + wv; n < NN; n += gridDim.x * 4) {
    const int beg = __builtin_amdgcn_readfirstlane(row_ptr[n]);
    const int end = __builtin_amdgcn_readfirstlane(row_ptr[n + 1]);
    float a[16];
#pragma unroll
    for (int k = 0; k < 16; ++k) a[k] = 0.0f;
    int j = beg;

#define GATHER_STEP(NK)                                                       \
  {                                                                           \
    u64 p[NK];                                                                \
    float v[NK];                                                              \
    _Pragma("unroll") for (int k = 0; k < NK; ++k)                            \
        p[k] = __builtin_nontemporal_load(&csr[j + k]);                       \
    _Pragma("unroll") for (int k = 0; k < NK; ++k)                            \
        v[k] = hw[(size_t)(unsigned)(p[k] & 0xffffffffu) * 64 + col];         \
    _Pragma("unroll") for (int k = 0; k < NK; ++k)                            \
        a[k] = fmaf(__uint_as_float((unsigned)(p[k] >> 32)), v[k], a[k]);     \
    j += NK;                                                                  \
  }

    while (j + 16 <= end) GATHER_STEP(16)
    if (j + 8 <= end) GATHER_STEP(8)
    if (j + 4 <= end) GATHER_STEP(4)
    if (j + 2 <= end) GATHER_STEP(2)
    if (j < end) GATHER_STEP(1)
#undef GATHER_STEP

    float acc = 0.0f;
#pragma unroll
    for (int k = 0; k < 8; ++k) acc += a[k] + a[k + 8];
    const size_t idx = (size_t)n * 64 + col;
    const float di = dinv[n];
    float v = fmaxf(acc + hw[idx] * di * di + brc, 0.0f);
    if (ADD_S) v += hs[idx];
    h[idx] = v;
  }
}

// -------- mean-pool: b is SORTED -> run-length accumulate, few atomics ------
__global__ __launch_bounds__(256) void k_pool(const float* __restrict__ h,
                                              const int* __restrict__ b,
                                              float* __restrict__ pool,
                                              float* __restrict__ cnt) {
  const int col = threadIdx.x & 63;
  const int wv  = threadIdx.x >> 6;
  const int node0 = (blockIdx.x * 4 + wv) * 64;  // 64 consecutive nodes per wave
  if (node0 >= NN) return;
  const int node1 = min(node0 + 64, NN);
  int gcur = b[node0];
  float acc = 0.f;
  float run = 0.f;
  for (int n = node0; n < node1; ++n) {
    const int g = b[n];  // wave-uniform broadcast load
    if (g != gcur) {
      atomicAdd(&pool[(size_t)gcur * 64 + col], acc);
      if (col == 0) atomicAdd(&cnt[gcur], run);
      gcur = g; acc = 0.f; run = 0.f;
    }
    acc += h[(size_t)n * 64 + col];
    run += 1.f;
  }
  atomicAdd(&pool[(size_t)gcur * 64 + col], acc);
  if (col == 0) atomicAdd(&cnt[gcur], run);
}

// ---------------- MLP head ----------------
__global__ __launch_bounds__(64) void k_head(const float* __restrict__ pool,
                                             const float* __restrict__ cnt,
                                             const float* __restrict__ lin1W,
                                             const float* __restrict__ lin1b,
                                             const float* __restrict__ lin2W,
                                             const float* __restrict__ lin2b,
                                             float* __restrict__ out) {
  const int g = blockIdx.x;
  const int lane = threadIdx.x;
  const float c = fmaxf(cnt[g], 1.0f);
  float r = 0.f;
  if (lane < 32) {
    float s = lin1b[lane];
    const float* p = pool + (size_t)g * 64;
#pragma unroll 8
    for (int ci = 0; ci < 64; ++ci) s = fmaf(p[ci] / c, lin1W[ci * 32 + lane], s);
    r = fmaxf(s, 0.0f) * lin2W[lane];
  }
  for (int off = 32; off > 0; off >>= 1) r += __shfl_down(r, off, 64);
  if (lane == 0) out[g] = r + lin2b[0];
}

extern "C" void kernel_launch(void* const* d_in, const int* in_sizes, int n_in,
                              void* d_out, int out_size, void* d_ws, size_t ws_size,
                              hipStream_t stream) {
  const float* x     = (const float*)d_in[0];
  const int*   src   = (const int*)d_in[1];            // e_idx[0]
  const int*   dst   = ((const int*)d_in[1]) + NE;     // e_idx[1]
  const int*   b     = (const int*)d_in[2];
  const float* w0    = (const float*)d_in[3];
  const float* b0    = (const float*)d_in[4];
  const float* convW = (const float*)d_in[5];
  const float* convB = (const float*)d_in[6];
  const float* skipW = (const float*)d_in[7];
  const float* skipB = (const float*)d_in[8];
  const float* lin1W = (const float*)d_in[9];
  const float* lin1b = (const float*)d_in[10];
  const float* lin2W = (const float*)d_in[11];
  const float* lin2b = (const float*)d_in[12];
  float* out = (float*)d_out;

  // ---- workspace layout (4-byte units, 102400-padded node arrays) ----
  char* w = (char*)d_ws;
  const size_t NPAD = 102400;
  int*    cnt     = (int*)w;                 w += NPAD * 4;
  float*  dinv    = (float*)w;               w += NPAD * 4;
  int*    row_ptr = (int*)w;                 w += NPAD * 4;   // NN+1 used
  int*    cursor  = (int*)w;                 w += NPAD * 4;
  int*    incl    = (int*)w;                 w += NPAD * 4;
  int*    bsum    = (int*)w;                 w += 512 * 4;
  int*    boff    = (int*)w;                 w += 512 * 4;
  float2* csr     = (float2*)w;              w += (size_t)NE * 8;
  float*  hA      = (float*)w;               w += (size_t)NN * 64 * 4;
  float*  hB      = (float*)w;               w += (size_t)NN * 64 * 4;
  float*  pool    = (float*)w;               w += (size_t)NG * 64 * 4;
  float*  pcnt    = (float*)w;               w += (size_t)NG * 4;

  const int EB = (NE + 255) / 256;

  // ---- CSR build (once per launch) ----
  hipMemsetAsync(cnt, 0, NN * sizeof(int), stream);
  k_hist<<<EB, 256, 0, stream>>>(dst, cnt);
  k_dinv<<<(NN + 255) / 256, 256, 0, stream>>>(cnt, dinv);
  k_scan_a<<<NB, SCAN_B, 0, stream>>>(cnt, incl, bsum);
  k_scan_b<<<1, 256, 0, stream>>>(bsum, boff);
  k_scan_c<<<NB, SCAN_B, 0, stream>>>(cnt, incl, boff, row_ptr, cursor);
  k_fill<<<EB, 256, 0, stream>>>(src, dst, dinv, cursor, csr);

  const u64* csru = (const u64*)csr;
  const int GT = (NN + 127) / 128;  // 782

  // ---- layer 0 ----
  k_gemm<NF, false><<<GT, 128, 0, stream>>>(x, w0, nullptr, nullptr, hB, nullptr);
  k_agg<false><<<2048, 256, 0, stream>>>(hB, nullptr, csru, row_ptr, dinv, b0, hA);
  // ---- layers 1..2 (conv+skip GEMMs fused; skip written in place into hA) ----
  for (int i = 0; i < 2; ++i) {
    k_gemm<H, true><<<GT, 128, 0, stream>>>(hA, convW + (size_t)i * H * H,
                                            skipW + (size_t)i * H * H,
                                            skipB + (size_t)i * H, hB, hA);
    k_agg<true><<<2048, 256, 0, stream>>>(hB, hA, csru, row_ptr, dinv,
                                          convB + (size_t)i * H, hA);
  }

  // ---- mean pool + head ----
  hipMemsetAsync(pool, 0, ((size_t)NG * 64 + NG) * sizeof(float), stream);
  k_pool<<<(NN / 256) + 1, 256, 0, stream>>>(hA, b, pool, pcnt);
  k_head<<<NG, 64, 0, stream>>>(pool, pcnt, lin1W, lin1b, lin2W, lin2b, out);
}

// Round 7
// 481.546 us; speedup vs baseline: 1.3278x; 1.3278x over previous
//
#include <hip/hip_runtime.h>

#define NN 100000      // nodes
#define NE 1600000     // edges
#define NF 128         // input features
#define H  64          // hidden channels
#define NG 4096        // graphs
#define SCAN_B 512
#define NB ((NN + SCAN_B - 1) / SCAN_B)   // 196 scan blocks
#define NPASS 4
#define PR (NN / NPASS)                   // 25000 dst-range per pass

typedef unsigned long long u64;

// ------- degree histogram, 4-pass dst-binned (L2-resident atomic window) ----
__global__ __launch_bounds__(256) void k_hist(const int* __restrict__ dst,
                                              int* __restrict__ cnt) {
  const int tid = blockIdx.x * blockDim.x + threadIdx.x;
  const int stride = gridDim.x * blockDim.x;
  for (int p = 0; p < NPASS; ++p) {
    const int lo = p * PR, hi = lo + PR;
    for (int e = tid; e < NE; e += stride) {
      const int d = dst[e];
      if (d >= lo && d < hi) atomicAdd(&cnt[d], 1);
    }
  }
}

__global__ __launch_bounds__(256) void k_dinv(const int* __restrict__ cnt,
                                              float* __restrict__ dinv) {
  int i = blockIdx.x * blockDim.x + threadIdx.x;
  if (i < NN) dinv[i] = 1.0f / sqrtf((float)cnt[i] + 1.0f);
}

// ---------------- 3-phase exclusive scan of cnt -> row_ptr ----------------
__global__ __launch_bounds__(SCAN_B) void k_scan_a(const int* __restrict__ cnt,
                                                   int* __restrict__ incl,
                                                   int* __restrict__ bsum) {
  __shared__ int sh[SCAN_B];
  const int i = blockIdx.x * SCAN_B + threadIdx.x;
  int v = (i < NN) ? cnt[i] : 0;
  sh[threadIdx.x] = v;
  __syncthreads();
  for (int off = 1; off < SCAN_B; off <<= 1) {
    int add = (threadIdx.x >= off) ? sh[threadIdx.x - off] : 0;
    __syncthreads();
    sh[threadIdx.x] += add;
    __syncthreads();
  }
  if (i < NN) incl[i] = sh[threadIdx.x];
  if (threadIdx.x == SCAN_B - 1) bsum[blockIdx.x] = sh[SCAN_B - 1];
}

__global__ __launch_bounds__(256) void k_scan_b(int* __restrict__ bsum,
                                                int* __restrict__ boff) {
  __shared__ int sh[256];
  const int t = threadIdx.x;
  int v = (t < NB) ? bsum[t] : 0;
  sh[t] = v;
  __syncthreads();
  for (int off = 1; off < 256; off <<= 1) {
    int add = (t >= off) ? sh[t - off] : 0;
    __syncthreads();
    sh[t] += add;
    __syncthreads();
  }
  if (t < NB) boff[t] = sh[t] - v;  // exclusive
}

__global__ __launch_bounds__(SCAN_B) void k_scan_c(const int* __restrict__ cnt,
                                                   const int* __restrict__ incl,
                                                   const int* __restrict__ boff,
                                                   int* __restrict__ row_ptr,
                                                   int* __restrict__ cursor) {
  const int i = blockIdx.x * SCAN_B + threadIdx.x;
  if (i < NN) {
    const int start = incl[i] + boff[blockIdx.x] - cnt[i];
    row_ptr[i] = start;
    cursor[i] = start;
  }
  if (i == 0) row_ptr[NN] = NE;
}

// ------- CSR fill, 4-pass dst-binned: csr window 3.2MB stays L2-resident ----
// Passes touch disjoint dst ranges -> disjoint csr/cursor ranges; no sync.
__global__ __launch_bounds__(256) void k_fill(const int* __restrict__ src,
                                              const int* __restrict__ dst,
                                              const float* __restrict__ dinv,
                                              int* __restrict__ cursor,
                                              float2* __restrict__ csr) {
  const int tid = blockIdx.x * blockDim.x + threadIdx.x;
  const int stride = gridDim.x * blockDim.x;
  for (int p = 0; p < NPASS; ++p) {
    const int lo = p * PR, hi = lo + PR;
    for (int e = tid; e < NE; e += stride) {
      const int d = dst[e];
      if (d >= lo && d < hi) {
        const int s = src[e];
        const int pos = atomicAdd(&cursor[d], 1);
        csr[pos] = make_float2(__int_as_float(s), dinv[s] * dinv[d]);
      }
    }
  }
}

// ---- node GEMM, LDS-tiled, micro-tile 8x4 --------------------------------
// Block 256 threads = tile 128 rows x 64 cols. Input chunk staged TRANSPOSED
// (tin[k][row], stride 132), weights staged [k][64]. Per-lane-distinct LDS
// reads (full BW). Thread (rg,cg) owns rows rg*8..+7, cols cg*4..+3.
// SK: skip GEMM fused (outS may alias in: block exclusively owns its 128
// rows; all global reads happen in staging, before any store).
template <int CI, bool SK>
__global__ __launch_bounds__(256) void k_gemm(const float* in,
                                              const float* __restrict__ W,
                                              const float* __restrict__ Ws,
                                              const float* __restrict__ bs,
                                              float* __restrict__ out,
                                              float* outS) {
  __shared__ float wt[CI * 64];
  __shared__ float wsl[SK ? 64 * 64 : 1];
  __shared__ float tin[32 * 132];
  for (int i = threadIdx.x; i < CI * 64; i += 256) wt[i] = W[i];
  if (SK)
    for (int i = threadIdx.x; i < 64 * 64; i += 256) wsl[i] = Ws[i];

  const int row0 = blockIdx.x * 128;
  const int rg = threadIdx.x >> 4;   // 0..15 (8 rows each)
  const int cg = threadIdx.x & 15;   // 0..15 (4 cols each)
  float acc[8][4];
  float sacc[SK ? 8 : 1][4];
  float sb[4];
#pragma unroll
  for (int j = 0; j < 4; ++j) sb[j] = SK ? bs[cg * 4 + j] : 0.0f;
#pragma unroll
  for (int i = 0; i < 8; ++i)
#pragma unroll
    for (int j = 0; j < 4; ++j) {
      acc[i][j] = 0.0f;
      if (SK) sacc[i][j] = sb[j];
    }

  for (int k0 = 0; k0 < CI; k0 += 32) {
    __syncthreads();  // previous chunk fully consumed
    // stage tin transposed: 4 sweeps of 32 rows; thread reads float4 of its row
    const int kk = (threadIdx.x & 7) * 4;
    const int rr = threadIdx.x >> 3;  // 0..31
#pragma unroll
    for (int s = 0; s < 4; ++s) {
      const int r = s * 32 + rr;
      const int rowc = min(row0 + r, NN - 1);
      const float4 v = *(const float4*)(in + (size_t)rowc * CI + k0 + kk);
      tin[(kk + 0) * 132 + r] = v.x;
      tin[(kk + 1) * 132 + r] = v.y;
      tin[(kk + 2) * 132 + r] = v.z;
      tin[(kk + 3) * 132 + r] = v.w;
    }
    __syncthreads();
#pragma unroll 4
    for (int k = 0; k < 32; ++k) {
      const float4 a0 = *(const float4*)&tin[k * 132 + rg * 8];
      const float4 a1 = *(const float4*)&tin[k * 132 + rg * 8 + 4];
      const float a[8] = {a0.x, a0.y, a0.z, a0.w, a1.x, a1.y, a1.z, a1.w};
      const float4 bw = *(const float4*)&wt[(k0 + k) * 64 + cg * 4];
#pragma unroll
      for (int i = 0; i < 8; ++i) {
        acc[i][0] = fmaf(a[i], bw.x, acc[i][0]);
        acc[i][1] = fmaf(a[i], bw.y, acc[i][1]);
        acc[i][2] = fmaf(a[i], bw.z, acc[i][2]);
        acc[i][3] = fmaf(a[i], bw.w, acc[i][3]);
      }
      if (SK) {
        const float4 bk = *(const float4*)&wsl[(k0 + k) * 64 + cg * 4];
#pragma unroll
        for (int i = 0; i < 8; ++i) {
          sacc[i][0] = fmaf(a[i], bk.x, sacc[i][0]);
          sacc[i][1] = fmaf(a[i], bk.y, sacc[i][1]);
          sacc[i][2] = fmaf(a[i], bk.z, sacc[i][2]);
          sacc[i][3] = fmaf(a[i], bk.w, sacc[i][3]);
        }
      }
    }
  }
  // write back (all staging reads complete -> in-place SK safe)
#pragma unroll
  for (int i = 0; i < 8; ++i) {
    const int row = row0 + rg * 8 + i;
    if (row < NN) {
      *(float4*)(out + (size_t)row * 64 + cg * 4) =
          make_float4(acc[i][0], acc[i][1], acc[i][2], acc[i][3]);
      if (SK)
        *(float4*)(outS + (size_t)row * 64 + cg * 4) =
            make_float4(sacc[i][0], sacc[i][1], sacc[i][2], sacc[i][3]);
    }
  }
}

// ------- CSR aggregation + finalize: h = relu(agg + hw*di^2 + bias) [+ hs] ---
// 16 independent row-gathers in flight; csr streamed nontemporal.
// ADD_S path runs with hs == h (read then write same addr, same thread).
template <bool ADD_S>
__global__ __launch_bounds__(256) void k_agg(const float* __restrict__ hw,
                                             const float* hs,
                                             const u64* __restrict__ csr,
                                             const int* __restrict__ row_ptr,
                                             const float* __restrict__ dinv,
                                             const float* __restrict__ bias,
                                             float* h) {
  const int col = threadIdx.x & 63;
  const int wv  = threadIdx.x >> 6;
  const float brc = bias[col];
  for (int n = blockIdx.x * 4 + wv; n < NN; n += gridDim.x * 4) {
    const int beg = __builtin_amdgcn_readfirstlane(row_ptr[n]);
    const int end = __builtin_amdgcn_readfirstlane(row_ptr[n + 1]);
    float a[16];
#pragma unroll
    for (int k = 0; k < 16; ++k) a[k] = 0.0f;
    int j = beg;

#define GATHER_STEP(NK)                                                       \
  {                                                                           \
    u64 p[NK];                                                                \
    float v[NK];                                                              \
    _Pragma("unroll") for (int k = 0; k < NK; ++k)                            \
        p[k] = __builtin_nontemporal_load(&csr[j + k]);                       \
    _Pragma("unroll") for (int k = 0; k < NK; ++k)                            \
        v[k] = hw[(size_t)(unsigned)(p[k] & 0xffffffffu) * 64 + col];         \
    _Pragma("unroll") for (int k = 0; k < NK; ++k)                            \
        a[k] = fmaf(__uint_as_float((unsigned)(p[k] >> 32)), v[k], a[k]);     \
    j += NK;                                                                  \
  }

    while (j + 16 <= end) GATHER_STEP(16)
    if (j + 8 <= end) GATHER_STEP(8)
    if (j + 4 <= end) GATHER_STEP(4)
    if (j + 2 <= end) GATHER_STEP(2)
    if (j < end) GATHER_STEP(1)
#undef GATHER_STEP

    float acc = 0.0f;
#pragma unroll
    for (int k = 0; k < 8; ++k) acc += a[k] + a[k + 8];
    const size_t idx = (size_t)n * 64 + col;
    const float di = dinv[n];
    float v = fmaxf(acc + hw[idx] * di * di + brc, 0.0f);
    if (ADD_S) v += hs[idx];
    h[idx] = v;
  }
}

// -------- mean-pool: b is SORTED -> run-length accumulate, few atomics ------
__global__ __launch_bounds__(256) void k_pool(const float* __restrict__ h,
                                              const int* __restrict__ b,
                                              float* __restrict__ pool,
                                              float* __restrict__ cnt) {
  const int col = threadIdx.x & 63;
  const int wv  = threadIdx.x >> 6;
  const int node0 = (blockIdx.x * 4 + wv) * 64;  // 64 consecutive nodes per wave
  if (node0 >= NN) return;
  const int node1 = min(node0 + 64, NN);
  int gcur = b[node0];
  float acc = 0.f;
  float run = 0.f;
  for (int n = node0; n < node1; ++n) {
    const int g = b[n];  // wave-uniform broadcast load
    if (g != gcur) {
      atomicAdd(&pool[(size_t)gcur * 64 + col], acc);
      if (col == 0) atomicAdd(&cnt[gcur], run);
      gcur = g; acc = 0.f; run = 0.f;
    }
    acc += h[(size_t)n * 64 + col];
    run += 1.f;
  }
  atomicAdd(&pool[(size_t)gcur * 64 + col], acc);
  if (col == 0) atomicAdd(&cnt[gcur], run);
}

// ---------------- MLP head ----------------
__global__ __launch_bounds__(64) void k_head(const float* __restrict__ pool,
                                             const float* __restrict__ cnt,
                                             const float* __restrict__ lin1W,
                                             const float* __restrict__ lin1b,
                                             const float* __restrict__ lin2W,
                                             const float* __restrict__ lin2b,
                                             float* __restrict__ out) {
  const int g = blockIdx.x;
  const int lane = threadIdx.x;
  const float c = fmaxf(cnt[g], 1.0f);
  float r = 0.f;
  if (lane < 32) {
    float s = lin1b[lane];
    const float* p = pool + (size_t)g * 64;
#pragma unroll 8
    for (int ci = 0; ci < 64; ++ci) s = fmaf(p[ci] / c, lin1W[ci * 32 + lane], s);
    r = fmaxf(s, 0.0f) * lin2W[lane];
  }
  for (int off = 32; off > 0; off >>= 1) r += __shfl_down(r, off, 64);
  if (lane == 0) out[g] = r + lin2b[0];
}

extern "C" void kernel_launch(void* const* d_in, const int* in_sizes, int n_in,
                              void* d_out, int out_size, void* d_ws, size_t ws_size,
                              hipStream_t stream) {
  const float* x     = (const float*)d_in[0];
  const int*   src   = (const int*)d_in[1];            // e_idx[0]
  const int*   dst   = ((const int*)d_in[1]) + NE;     // e_idx[1]
  const int*   b     = (const int*)d_in[2];
  const float* w0    = (const float*)d_in[3];
  const float* b0    = (const float*)d_in[4];
  const float* convW = (const float*)d_in[5];
  const float* convB = (const float*)d_in[6];
  const float* skipW = (const float*)d_in[7];
  const float* skipB = (const float*)d_in[8];
  const float* lin1W = (const float*)d_in[9];
  const float* lin1b = (const float*)d_in[10];
  const float* lin2W = (const float*)d_in[11];
  const float* lin2b = (const float*)d_in[12];
  float* out = (float*)d_out;

  // ---- workspace layout (4-byte units, 102400-padded node arrays) ----
  char* w = (char*)d_ws;
  const size_t NPAD = 102400;
  int*    cnt     = (int*)w;                 w += NPAD * 4;
  float*  dinv    = (float*)w;               w += NPAD * 4;
  int*    row_ptr = (int*)w;                 w += NPAD * 4;   // NN+1 used
  int*    cursor  = (int*)w;                 w += NPAD * 4;
  int*    incl    = (int*)w;                 w += NPAD * 4;
  int*    bsum    = (int*)w;                 w += 512 * 4;
  int*    boff    = (int*)w;                 w += 512 * 4;
  float2* csr     = (float2*)w;              w += (size_t)NE * 8;
  float*  hA      = (float*)w;               w += (size_t)NN * 64 * 4;
  float*  hB      = (float*)w;               w += (size_t)NN * 64 * 4;
  float*  pool    = (float*)w;               w += (size_t)NG * 64 * 4;
  float*  pcnt    = (float*)w;               w += (size_t)NG * 4;

  // ---- CSR build (once per launch) ----
  hipMemsetAsync(cnt, 0, NN * sizeof(int), stream);
  k_hist<<<2048, 256, 0, stream>>>(dst, cnt);
  k_dinv<<<(NN + 255) / 256, 256, 0, stream>>>(cnt, dinv);
  k_scan_a<<<NB, SCAN_B, 0, stream>>>(cnt, incl, bsum);
  k_scan_b<<<1, 256, 0, stream>>>(bsum, boff);
  k_scan_c<<<NB, SCAN_B, 0, stream>>>(cnt, incl, boff, row_ptr, cursor);
  k_fill<<<2048, 256, 0, stream>>>(src, dst, dinv, cursor, csr);

  const u64* csru = (const u64*)csr;
  const int GT = (NN + 127) / 128;  // 782 tiles

  // ---- layer 0 ----
  k_gemm<NF, false><<<GT, 256, 0, stream>>>(x, w0, nullptr, nullptr, hB, nullptr);
  k_agg<false><<<2048, 256, 0, stream>>>(hB, nullptr, csru, row_ptr, dinv, b0, hA);
  // ---- layers 1..2 (conv+skip GEMMs fused; skip written in place into hA) ----
  for (int i = 0; i < 2; ++i) {
    k_gemm<H, true><<<GT, 256, 0, stream>>>(hA, convW + (size_t)i * H * H,
                                            skipW + (size_t)i * H * H,
                                            skipB + (size_t)i * H, hB, hA);
    k_agg<true><<<2048, 256, 0, stream>>>(hB, hA, csru, row_ptr, dinv,
                                          convB + (size_t)i * H, hA);
  }

  // ---- mean pool + head ----
  hipMemsetAsync(pool, 0, ((size_t)NG * 64 + NG) * sizeof(float), stream);
  k_pool<<<(NN / 256) + 1, 256, 0, stream>>>(hA, b, pool, pcnt);
  k_head<<<NG, 64, 0, stream>>>(pool, pcnt, lin1W, lin1b, lin2W, lin2b, out);
}

// Round 8
// 423.861 us; speedup vs baseline: 1.5085x; 1.1361x over previous
//
#include <hip/hip_runtime.h>

#define NN 100000      // nodes
#define NE 1600000     // edges
#define NF 128         // input features
#define H  64          // hidden channels
#define NG 4096        // graphs

#define NBK 512        // dst buckets
#define BKN 196        // nodes per bucket (512*196 >= NN)
#define CAP 4096       // edge capacity per bucket (avg 3136, sigma 56)
#define NBLK_BIN 128
#define CHUNK ((NE + NBLK_BIN - 1) / NBLK_BIN)   // 12500

typedef unsigned long long u64;

// ---- phase 1: bucket-bin edges, block-local runs (line-local writes) ------
__global__ __launch_bounds__(256) void k_bin(const int* __restrict__ src,
                                             const int* __restrict__ dst,
                                             int* __restrict__ bcur,
                                             u64* __restrict__ ebuf) {
  __shared__ int bcnt[NBK];
  __shared__ int bpos[NBK];
  const int e0 = blockIdx.x * CHUNK;
  const int e1 = min(e0 + CHUNK, NE);
  for (int i = threadIdx.x; i < NBK; i += 256) bcnt[i] = 0;
  __syncthreads();
  for (int e = e0 + threadIdx.x; e < e1; e += 256)
    atomicAdd(&bcnt[dst[e] / BKN], 1);
  __syncthreads();
  for (int i = threadIdx.x; i < NBK; i += 256) {
    const int c = bcnt[i];
    if (c) bpos[i] = i * CAP + atomicAdd(&bcur[i], c);
  }
  __syncthreads();
  for (int e = e0 + threadIdx.x; e < e1; e += 256) {
    const int d = dst[e];
    const int pos = atomicAdd(&bpos[d / BKN], 1);
    ebuf[pos] = ((u64)(unsigned)d << 32) | (unsigned)src[e];
  }
}

// ---- phase 2: per-bucket CSR build (one block owns one bucket) ------------
__global__ __launch_bounds__(256) void k_csr(const int* __restrict__ bcur,
                                             const u64* __restrict__ ebuf,
                                             int* __restrict__ row_ptr,
                                             int* __restrict__ cnt,
                                             float* __restrict__ dinv,
                                             int* __restrict__ csr_src) {
  __shared__ int deg[256], sc[256], cur[256];
  const int bk = blockIdx.x;
  const int nlo = bk * BKN;
  if (nlo >= NN) return;
  const int nloc = min(BKN, NN - nlo);
  const int cntE = bcur[bk];
  const int t = threadIdx.x;
  deg[t] = 0;
  __syncthreads();
  const u64* eb = ebuf + (size_t)bk * CAP;
  for (int e = t; e < cntE; e += 256)
    atomicAdd(&deg[(int)(eb[e] >> 32) - nlo], 1);
  __syncthreads();
  sc[t] = deg[t];
  __syncthreads();
  for (int off = 1; off < 256; off <<= 1) {
    const int add = (t >= off) ? sc[t - off] : 0;
    __syncthreads();
    sc[t] += add;
    __syncthreads();
  }
  const int excl = bk * CAP + sc[t] - deg[t];
  if (t < nloc) {
    row_ptr[nlo + t] = excl;
    cnt[nlo + t] = deg[t];
    dinv[nlo + t] = 1.0f / sqrtf((float)deg[t] + 1.0f);
  }
  cur[t] = excl;
  __syncthreads();
  for (int e = t; e < cntE; e += 256) {
    const u64 ent = eb[e];
    const int d = (int)(ent >> 32) - nlo;
    const int pos = atomicAdd(&cur[d], 1);
    csr_src[pos] = (int)(unsigned)(ent & 0xffffffffu);
  }
}

// ---- node GEMM, LDS-tiled, micro-tile 8x4; epilogue scales by dinv[row] ---
// out[n,:] = (in[n,:]@W) * dinv[n]   (pre-scaled for aggregation)
// SK: outS[n,:] = in[n,:]@Ws + bs (UNSCALED skip), may alias in (block owns
// its 128 rows exclusively; all global reads happen in staging before stores).
template <int CI, bool SK>
__global__ __launch_bounds__(256) void k_gemm(const float* in,
                                              const float* __restrict__ W,
                                              const float* __restrict__ Ws,
                                              const float* __restrict__ bs,
                                              const float* __restrict__ dinv,
                                              float* __restrict__ out,
                                              float* outS) {
  __shared__ float wt[CI * 64];
  __shared__ float wsl[SK ? 64 * 64 : 1];
  __shared__ float tin[32 * 132];
  for (int i = threadIdx.x; i < CI * 64; i += 256) wt[i] = W[i];
  if (SK)
    for (int i = threadIdx.x; i < 64 * 64; i += 256) wsl[i] = Ws[i];

  const int row0 = blockIdx.x * 128;
  const int rg = threadIdx.x >> 4;   // 0..15 (8 rows each)
  const int cg = threadIdx.x & 15;   // 0..15 (4 cols each)
  float acc[8][4];
  float sacc[SK ? 8 : 1][4];
  float sb[4];
#pragma unroll
  for (int j = 0; j < 4; ++j) sb[j] = SK ? bs[cg * 4 + j] : 0.0f;
#pragma unroll
  for (int i = 0; i < 8; ++i)
#pragma unroll
    for (int j = 0; j < 4; ++j) {
      acc[i][j] = 0.0f;
      if (SK) sacc[i][j] = sb[j];
    }

  for (int k0 = 0; k0 < CI; k0 += 32) {
    __syncthreads();  // previous chunk fully consumed
    const int kk = (threadIdx.x & 7) * 4;
    const int rr = threadIdx.x >> 3;  // 0..31
#pragma unroll
    for (int s = 0; s < 4; ++s) {
      const int r = s * 32 + rr;
      const int rowc = min(row0 + r, NN - 1);
      const float4 v = *(const float4*)(in + (size_t)rowc * CI + k0 + kk);
      tin[(kk + 0) * 132 + r] = v.x;
      tin[(kk + 1) * 132 + r] = v.y;
      tin[(kk + 2) * 132 + r] = v.z;
      tin[(kk + 3) * 132 + r] = v.w;
    }
    __syncthreads();
#pragma unroll 4
    for (int k = 0; k < 32; ++k) {
      const float4 a0 = *(const float4*)&tin[k * 132 + rg * 8];
      const float4 a1 = *(const float4*)&tin[k * 132 + rg * 8 + 4];
      const float a[8] = {a0.x, a0.y, a0.z, a0.w, a1.x, a1.y, a1.z, a1.w};
      const float4 bw = *(const float4*)&wt[(k0 + k) * 64 + cg * 4];
#pragma unroll
      for (int i = 0; i < 8; ++i) {
        acc[i][0] = fmaf(a[i], bw.x, acc[i][0]);
        acc[i][1] = fmaf(a[i], bw.y, acc[i][1]);
        acc[i][2] = fmaf(a[i], bw.z, acc[i][2]);
        acc[i][3] = fmaf(a[i], bw.w, acc[i][3]);
      }
      if (SK) {
        const float4 bk = *(const float4*)&wsl[(k0 + k) * 64 + cg * 4];
#pragma unroll
        for (int i = 0; i < 8; ++i) {
          sacc[i][0] = fmaf(a[i], bk.x, sacc[i][0]);
          sacc[i][1] = fmaf(a[i], bk.y, sacc[i][1]);
          sacc[i][2] = fmaf(a[i], bk.z, sacc[i][2]);
          sacc[i][3] = fmaf(a[i], bk.w, sacc[i][3]);
        }
      }
    }
  }
#pragma unroll
  for (int i = 0; i < 8; ++i) {
    const int row = row0 + rg * 8 + i;
    if (row < NN) {
      const float dv = dinv[row];
      *(float4*)(out + (size_t)row * 64 + cg * 4) =
          make_float4(acc[i][0] * dv, acc[i][1] * dv, acc[i][2] * dv,
                      acc[i][3] * dv);
      if (SK)
        *(float4*)(outS + (size_t)row * 64 + cg * 4) =
            make_float4(sacc[i][0], sacc[i][1], sacc[i][2], sacc[i][3]);
    }
  }
}

// ------- CSR aggregation + finalize ----------------------------------------
// hwp is PRE-SCALED (hw*dinv). h = relu(dinv_d*(sum + hwp[d]) + bias) [+ hs]
// 16 independent row-gathers in flight; 4B src-only csr entries.
// ADD_S path runs with hs == h (read then write same addr, same thread).
template <bool ADD_S>
__global__ __launch_bounds__(256) void k_agg(const float* __restrict__ hwp,
                                             const float* hs,
                                             const int* __restrict__ csr_src,
                                             const int* __restrict__ row_ptr,
                                             const int* __restrict__ cnt,
                                             const float* __restrict__ dinv,
                                             const float* __restrict__ bias,
                                             float* h) {
  const int col = threadIdx.x & 63;
  const int wv  = threadIdx.x >> 6;
  const float brc = bias[col];
  for (int n = blockIdx.x * 4 + wv; n < NN; n += gridDim.x * 4) {
    const int beg = __builtin_amdgcn_readfirstlane(row_ptr[n]);
    const int end = beg + __builtin_amdgcn_readfirstlane(cnt[n]);
    float a[16];
#pragma unroll
    for (int k = 0; k < 16; ++k) a[k] = 0.0f;
    int j = beg;

#define GATHER_STEP(NK)                                                       \
  {                                                                           \
    int p[NK];                                                                \
    float v[NK];                                                              \
    _Pragma("unroll") for (int k = 0; k < NK; ++k)                            \
        p[k] = __builtin_nontemporal_load(&csr_src[j + k]);                   \
    _Pragma("unroll") for (int k = 0; k < NK; ++k)                            \
        v[k] = hwp[(size_t)p[k] * 64 + col];                                  \
    _Pragma("unroll") for (int k = 0; k < NK; ++k) a[k] += v[k];              \
    j += NK;                                                                  \
  }

    while (j + 16 <= end) GATHER_STEP(16)
    if (j + 8 <= end) GATHER_STEP(8)
    if (j + 4 <= end) GATHER_STEP(4)
    if (j + 2 <= end) GATHER_STEP(2)
    if (j < end) GATHER_STEP(1)
#undef GATHER_STEP

    float acc = 0.0f;
#pragma unroll
    for (int k = 0; k < 8; ++k) acc += a[k] + a[k + 8];
    const size_t idx = (size_t)n * 64 + col;
    float v = fmaxf((acc + hwp[idx]) * dinv[n] + brc, 0.0f);
    if (ADD_S) v += hs[idx];
    h[idx] = v;
  }
}

// -------- mean-pool: b is SORTED -> run-length accumulate, few atomics ------
__global__ __launch_bounds__(256) void k_pool(const float* __restrict__ h,
                                              const int* __restrict__ b,
                                              float* __restrict__ pool,
                                              float* __restrict__ cnt) {
  const int col = threadIdx.x & 63;
  const int wv  = threadIdx.x >> 6;
  const int node0 = (blockIdx.x * 4 + wv) * 64;  // 64 consecutive nodes per wave
  if (node0 >= NN) return;
  const int node1 = min(node0 + 64, NN);
  int gcur = b[node0];
  float acc = 0.f;
  float run = 0.f;
  for (int n = node0; n < node1; ++n) {
    const int g = b[n];  // wave-uniform broadcast load
    if (g != gcur) {
      atomicAdd(&pool[(size_t)gcur * 64 + col], acc);
      if (col == 0) atomicAdd(&cnt[gcur], run);
      gcur = g; acc = 0.f; run = 0.f;
    }
    acc += h[(size_t)n * 64 + col];
    run += 1.f;
  }
  atomicAdd(&pool[(size_t)gcur * 64 + col], acc);
  if (col == 0) atomicAdd(&cnt[gcur], run);
}

// ---------------- MLP head ----------------
__global__ __launch_bounds__(64) void k_head(const float* __restrict__ pool,
                                             const float* __restrict__ cnt,
                                             const float* __restrict__ lin1W,
                                             const float* __restrict__ lin1b,
                                             const float* __restrict__ lin2W,
                                             const float* __restrict__ lin2b,
                                             float* __restrict__ out) {
  const int g = blockIdx.x;
  const int lane = threadIdx.x;
  const float c = fmaxf(cnt[g], 1.0f);
  float r = 0.f;
  if (lane < 32) {
    float s = lin1b[lane];
    const float* p = pool + (size_t)g * 64;
#pragma unroll 8
    for (int ci = 0; ci < 64; ++ci) s = fmaf(p[ci] / c, lin1W[ci * 32 + lane], s);
    r = fmaxf(s, 0.0f) * lin2W[lane];
  }
  for (int off = 32; off > 0; off >>= 1) r += __shfl_down(r, off, 64);
  if (lane == 0) out[g] = r + lin2b[0];
}

extern "C" void kernel_launch(void* const* d_in, const int* in_sizes, int n_in,
                              void* d_out, int out_size, void* d_ws, size_t ws_size,
                              hipStream_t stream) {
  const float* x     = (const float*)d_in[0];
  const int*   src   = (const int*)d_in[1];            // e_idx[0]
  const int*   dst   = ((const int*)d_in[1]) + NE;     // e_idx[1]
  const int*   b     = (const int*)d_in[2];
  const float* w0    = (const float*)d_in[3];
  const float* b0    = (const float*)d_in[4];
  const float* convW = (const float*)d_in[5];
  const float* convB = (const float*)d_in[6];
  const float* skipW = (const float*)d_in[7];
  const float* skipB = (const float*)d_in[8];
  const float* lin1W = (const float*)d_in[9];
  const float* lin1b = (const float*)d_in[10];
  const float* lin2W = (const float*)d_in[11];
  const float* lin2b = (const float*)d_in[12];
  float* out = (float*)d_out;

  // ---- workspace layout ----
  char* w = (char*)d_ws;
  const size_t NPAD = 102400;
  int*   cnt     = (int*)w;                  w += NPAD * 4;
  float* dinv    = (float*)w;                w += NPAD * 4;
  int*   row_ptr = (int*)w;                  w += NPAD * 4;
  int*   bcur    = (int*)w;                  w += 1024 * 4;
  u64*   ebuf    = (u64*)w;                  w += (size_t)NBK * CAP * 8;
  int*   csr_src = (int*)w;                  w += (size_t)NBK * CAP * 4;
  float* hA      = (float*)w;                w += (size_t)NN * 64 * 4;
  float* hB      = (float*)w;                w += (size_t)NN * 64 * 4;
  float* pool    = (float*)w;                w += (size_t)NG * 64 * 4;
  float* pcnt    = (float*)w;                w += (size_t)NG * 4;

  // ---- CSR build: block-local bucket sort (once per launch) ----
  hipMemsetAsync(bcur, 0, NBK * sizeof(int), stream);
  k_bin<<<NBLK_BIN, 256, 0, stream>>>(src, dst, bcur, ebuf);
  k_csr<<<NBK, 256, 0, stream>>>(bcur, ebuf, row_ptr, cnt, dinv, csr_src);

  const int GT = (NN + 127) / 128;  // 782 tiles

  // ---- layer 0 ----
  k_gemm<NF, false><<<GT, 256, 0, stream>>>(x, w0, nullptr, nullptr, dinv, hB,
                                            nullptr);
  k_agg<false><<<2048, 256, 0, stream>>>(hB, nullptr, csr_src, row_ptr, cnt,
                                         dinv, b0, hA);
  // ---- layers 1..2 (conv+skip GEMMs fused; skip written in place into hA) ----
  for (int i = 0; i < 2; ++i) {
    k_gemm<H, true><<<GT, 256, 0, stream>>>(hA, convW + (size_t)i * H * H,
                                            skipW + (size_t)i * H * H,
                                            skipB + (size_t)i * H, dinv, hB, hA);
    k_agg<true><<<2048, 256, 0, stream>>>(hB, hA, csr_src, row_ptr, cnt, dinv,
                                          convB + (size_t)i * H, hA);
  }

  // ---- mean pool + head ----
  hipMemsetAsync(pool, 0, ((size_t)NG * 64 + NG) * sizeof(float), stream);
  k_pool<<<(NN / 256) + 1, 256, 0, stream>>>(hA, b, pool, pcnt);
  k_head<<<NG, 64, 0, stream>>>(pool, pcnt, lin1W, lin1b, lin2W, lin2b, out);
}

// Round 9
// 366.502 us; speedup vs baseline: 1.7445x; 1.1565x over previous
//
#include <hip/hip_runtime.h>
#include <hip/hip_fp16.h>

#define NN 100000      // nodes
#define NE 1600000     // edges
#define NF 128         // input features
#define H  64          // hidden channels
#define NG 4096        // graphs

#define NBK 512        // dst buckets
#define BKN 196        // nodes per bucket
#define CAP 4096       // edge capacity per bucket (avg 3125, sigma 56)
#define NBLK_BIN 128
#define CHUNK ((NE + NBLK_BIN - 1) / NBLK_BIN)   // 12500

typedef unsigned long long u64;
typedef unsigned int u32;

__device__ inline u32 packh2(float x, float y) {
  __half2 h = __floats2half2_rn(x, y);
  return *reinterpret_cast<u32*>(&h);
}
__device__ inline float2 unpackh2(u32 u) {
  __half2 h = *reinterpret_cast<__half2*>(&u);
  return __half22float2(h);
}

// ---- phase 1: bucket-bin edges, block-local runs (line-local writes) ------
__global__ __launch_bounds__(256) void k_bin(const int* __restrict__ src,
                                             const int* __restrict__ dst,
                                             int* __restrict__ bcur,
                                             u64* __restrict__ ebuf) {
  __shared__ int bcnt[NBK];
  __shared__ int bpos[NBK];
  const int e0 = blockIdx.x * CHUNK;
  const int e1 = min(e0 + CHUNK, NE);
  for (int i = threadIdx.x; i < NBK; i += 256) bcnt[i] = 0;
  __syncthreads();
  for (int e = e0 + threadIdx.x; e < e1; e += 256)
    atomicAdd(&bcnt[dst[e] / BKN], 1);
  __syncthreads();
  for (int i = threadIdx.x; i < NBK; i += 256) {
    const int c = bcnt[i];
    if (c) bpos[i] = i * CAP + atomicAdd(&bcur[i], c);
  }
  __syncthreads();
  for (int e = e0 + threadIdx.x; e < e1; e += 256) {
    const int d = dst[e];
    const int pos = atomicAdd(&bpos[d / BKN], 1);
    ebuf[pos] = ((u64)(unsigned)d << 32) | (unsigned)src[e];
  }
}

// ---- phase 2: per-bucket CSR build (one block owns one bucket) ------------
__global__ __launch_bounds__(256) void k_csr(const int* __restrict__ bcur,
                                             const u64* __restrict__ ebuf,
                                             int* __restrict__ row_ptr,
                                             int* __restrict__ cnt,
                                             float* __restrict__ dinv,
                                             int* __restrict__ csr_src) {
  __shared__ int deg[256], sc[256], cur[256];
  const int bk = blockIdx.x;
  const int nlo = bk * BKN;
  if (nlo >= NN) return;
  const int nloc = min(BKN, NN - nlo);
  const int cntE = bcur[bk];
  const int t = threadIdx.x;
  deg[t] = 0;
  __syncthreads();
  const u64* eb = ebuf + (size_t)bk * CAP;
  for (int e = t; e < cntE; e += 256)
    atomicAdd(&deg[(int)(eb[e] >> 32) - nlo], 1);
  __syncthreads();
  sc[t] = deg[t];
  __syncthreads();
  for (int off = 1; off < 256; off <<= 1) {
    const int add = (t >= off) ? sc[t - off] : 0;
    __syncthreads();
    sc[t] += add;
    __syncthreads();
  }
  const int excl = bk * CAP + sc[t] - deg[t];
  if (t < nloc) {
    row_ptr[nlo + t] = excl;
    cnt[nlo + t] = deg[t];
    dinv[nlo + t] = 1.0f / sqrtf((float)deg[t] + 1.0f);
  }
  cur[t] = excl;
  __syncthreads();
  for (int e = t; e < cntE; e += 256) {
    const u64 ent = eb[e];
    const int d = (int)(ent >> 32) - nlo;
    const int pos = atomicAdd(&cur[d], 1);
    csr_src[pos] = (int)(unsigned)(ent & 0xffffffffu);
  }
}

// ---- node GEMM, LDS-tiled, micro-tile 8x8 ---------------------------------
// Block 256 threads = tile 256 rows x 64 cols. k-chunks of 16 staged
// transposed in tin with 48B group stride (bank-spread). Epilogue scales by
// dinv[row] and packs fp16 pairs -> out16 (the gather array).
// SK: skip GEMM fused, fp32 result to outS (no aliasing anywhere).
template <int CI, bool SK>
__global__ __launch_bounds__(256) void k_gemm(const float* __restrict__ in,
                                              const float* __restrict__ W,
                                              const float* __restrict__ Ws,
                                              const float* __restrict__ bs,
                                              const float* __restrict__ dinv,
                                              u32* __restrict__ out16,
                                              float* __restrict__ outS) {
  __shared__ float wt[CI * 64];
  __shared__ float wsl[SK ? 64 * 64 : 1];
  __shared__ float tin[16 * 384];  // [k][ (r>>3)*12 + (r&7) ]
  for (int i = threadIdx.x; i < CI * 64; i += 256) wt[i] = W[i];
  if (SK)
    for (int i = threadIdx.x; i < 64 * 64; i += 256) wsl[i] = Ws[i];

  const int row0 = blockIdx.x * 256;
  const int rg = threadIdx.x >> 3;  // 0..31: 8-row group
  const int cg = threadIdx.x & 7;   // 0..7 : 8-col group
  float acc[8][8];
  float sacc[SK ? 8 : 1][SK ? 8 : 1];
#pragma unroll
  for (int i = 0; i < 8; ++i)
#pragma unroll
    for (int j = 0; j < 8; ++j) acc[i][j] = 0.0f;
  if (SK) {
#pragma unroll
    for (int i = 0; i < 8; ++i)
#pragma unroll
      for (int j = 0; j < 8; ++j) sacc[i][j] = bs[cg * 8 + j];
  }

  for (int k0 = 0; k0 < CI; k0 += 16) {
    __syncthreads();  // previous chunk fully consumed
    const int kk = (threadIdx.x & 3) * 4;
    const int rr = threadIdx.x >> 2;  // 0..63
#pragma unroll
    for (int s = 0; s < 4; ++s) {
      const int r = s * 64 + rr;
      const int rowc = min(row0 + r, NN - 1);
      const float4 v = *(const float4*)(in + (size_t)rowc * CI + k0 + kk);
      const int base = (r >> 3) * 12 + (r & 7);
      tin[(kk + 0) * 384 + base] = v.x;
      tin[(kk + 1) * 384 + base] = v.y;
      tin[(kk + 2) * 384 + base] = v.z;
      tin[(kk + 3) * 384 + base] = v.w;
    }
    __syncthreads();
#pragma unroll 4
    for (int k = 0; k < 16; ++k) {
      const float4 a0 = *(const float4*)&tin[k * 384 + rg * 12];
      const float4 a1 = *(const float4*)&tin[k * 384 + rg * 12 + 4];
      const float af[8] = {a0.x, a0.y, a0.z, a0.w, a1.x, a1.y, a1.z, a1.w};
      const float4 b0 = *(const float4*)&wt[(k0 + k) * 64 + cg * 8];
      const float4 b1 = *(const float4*)&wt[(k0 + k) * 64 + cg * 8 + 4];
      const float bf[8] = {b0.x, b0.y, b0.z, b0.w, b1.x, b1.y, b1.z, b1.w};
#pragma unroll
      for (int i = 0; i < 8; ++i)
#pragma unroll
        for (int j = 0; j < 8; ++j) acc[i][j] = fmaf(af[i], bf[j], acc[i][j]);
      if (SK) {
        const float4 c0 = *(const float4*)&wsl[(k0 + k) * 64 + cg * 8];
        const float4 c1 = *(const float4*)&wsl[(k0 + k) * 64 + cg * 8 + 4];
        const float cf[8] = {c0.x, c0.y, c0.z, c0.w, c1.x, c1.y, c1.z, c1.w};
#pragma unroll
        for (int i = 0; i < 8; ++i)
#pragma unroll
          for (int j = 0; j < 8; ++j) sacc[i][j] = fmaf(af[i], cf[j], sacc[i][j]);
      }
    }
  }
#pragma unroll
  for (int i = 0; i < 8; ++i) {
    const int row = row0 + rg * 8 + i;
    if (row < NN) {
      const float dv = dinv[row];
      u32 o[4];
#pragma unroll
      for (int j = 0; j < 4; ++j)
        o[j] = packh2(acc[i][2 * j] * dv, acc[i][2 * j + 1] * dv);
      *(uint4*)&out16[(size_t)row * 32 + cg * 4] =
          make_uint4(o[0], o[1], o[2], o[3]);
      if (SK) {
        float* sp = outS + (size_t)row * 64 + cg * 8;
        *(float4*)(sp) = make_float4(sacc[i][0], sacc[i][1], sacc[i][2], sacc[i][3]);
        *(float4*)(sp + 4) = make_float4(sacc[i][4], sacc[i][5], sacc[i][6], sacc[i][7]);
      }
    }
  }
}

// ------- CSR aggregation + finalize (fp16 gather) ---------------------------
// wave = 2 nodes x 32 lanes; lane owns a col PAIR (one u32 = 2 fp16).
// h = relu((sum_nbrs + self) * dinv_d + bias) [+ hs]; accumulation in fp32.
template <bool ADD_S>
__global__ __launch_bounds__(256) void k_agg(const u32* __restrict__ hw16,
                                             const float* __restrict__ hs,
                                             const int* __restrict__ csr_src,
                                             const int* __restrict__ row_ptr,
                                             const int* __restrict__ cnt,
                                             const float* __restrict__ dinv,
                                             const float* __restrict__ bias,
                                             float* __restrict__ h) {
  const int lane = threadIdx.x & 31;        // col-pair index
  const int half = (threadIdx.x >> 5) & 1;  // node within pair
  const int wv = threadIdx.x >> 6;          // wave 0..3
  const int n = (blockIdx.x * 4 + wv) * 2 + half;  // NN = 12500*8 exactly
  const int beg = row_ptr[n];   // uniform within half-wave (broadcast)
  const int deg = cnt[n];
  const int dm = max(deg, __shfl_xor(deg, 32));
  float2 a[8];
#pragma unroll
  for (int k = 0; k < 8; ++k) a[k] = make_float2(0.0f, 0.0f);
  int i = 0;

#define GSTEP(NK)                                                             \
  {                                                                           \
    int p[NK];                                                                \
    u32 uv[NK];                                                               \
    _Pragma("unroll") for (int k = 0; k < NK; ++k) {                          \
      int e = i + k;                                                          \
      e = e < deg ? e : deg - 1;                                              \
      e = e > 0 ? e : 0;                                                      \
      p[k] = __builtin_nontemporal_load(&csr_src[beg + e]);                   \
    }                                                                         \
    _Pragma("unroll") for (int k = 0; k < NK; ++k)                            \
        uv[k] = hw16[(size_t)p[k] * 32 + lane];                               \
    _Pragma("unroll") for (int k = 0; k < NK; ++k) {                          \
      const float2 f = unpackh2(uv[k]);                                       \
      const bool ok = (i + k) < deg;                                          \
      a[k & 7].x += ok ? f.x : 0.0f;                                          \
      a[k & 7].y += ok ? f.y : 0.0f;                                          \
    }                                                                         \
    i += NK;                                                                  \
  }

  while (i + 16 <= dm) GSTEP(16)
  if (i + 8 <= dm) GSTEP(8)
  if (i + 4 <= dm) GSTEP(4)
  if (i + 2 <= dm) GSTEP(2)
  if (i < dm) GSTEP(1)
#undef GSTEP

  float2 t0 = make_float2(a[0].x + a[1].x, a[0].y + a[1].y);
  float2 t1 = make_float2(a[2].x + a[3].x, a[2].y + a[3].y);
  float2 t2 = make_float2(a[4].x + a[5].x, a[4].y + a[5].y);
  float2 t3 = make_float2(a[6].x + a[7].x, a[6].y + a[7].y);
  float2 acc = make_float2((t0.x + t1.x) + (t2.x + t3.x),
                           (t0.y + t1.y) + (t2.y + t3.y));
  const float2 self = unpackh2(hw16[(size_t)n * 32 + lane]);
  const float dv = dinv[n];
  const float2 brc = *(const float2*)&bias[2 * lane];
  float2 r;
  r.x = fmaxf((acc.x + self.x) * dv + brc.x, 0.0f);
  r.y = fmaxf((acc.y + self.y) * dv + brc.y, 0.0f);
  if (ADD_S) {
    const float2 s = *(const float2*)&hs[(size_t)n * 64 + 2 * lane];
    r.x += s.x;
    r.y += s.y;
  }
  *(float2*)&h[(size_t)n * 64 + 2 * lane] = r;
}

// -------- mean-pool: b is SORTED -> run-length accumulate, few atomics ------
__global__ __launch_bounds__(256) void k_pool(const float* __restrict__ h,
                                              const int* __restrict__ b,
                                              float* __restrict__ pool,
                                              float* __restrict__ cnt) {
  const int col = threadIdx.x & 63;
  const int wv  = threadIdx.x >> 6;
  const int node0 = (blockIdx.x * 4 + wv) * 64;
  if (node0 >= NN) return;
  const int node1 = min(node0 + 64, NN);
  int gcur = b[node0];
  float acc = 0.f;
  float run = 0.f;
  for (int n = node0; n < node1; ++n) {
    const int g = b[n];  // wave-uniform broadcast load
    if (g != gcur) {
      atomicAdd(&pool[(size_t)gcur * 64 + col], acc);
      if (col == 0) atomicAdd(&cnt[gcur], run);
      gcur = g; acc = 0.f; run = 0.f;
    }
    acc += h[(size_t)n * 64 + col];
    run += 1.f;
  }
  atomicAdd(&pool[(size_t)gcur * 64 + col], acc);
  if (col == 0) atomicAdd(&cnt[gcur], run);
}

// ---------------- MLP head ----------------
__global__ __launch_bounds__(64) void k_head(const float* __restrict__ pool,
                                             const float* __restrict__ cnt,
                                             const float* __restrict__ lin1W,
                                             const float* __restrict__ lin1b,
                                             const float* __restrict__ lin2W,
                                             const float* __restrict__ lin2b,
                                             float* __restrict__ out) {
  const int g = blockIdx.x;
  const int lane = threadIdx.x;
  const float c = fmaxf(cnt[g], 1.0f);
  float r = 0.f;
  if (lane < 32) {
    float s = lin1b[lane];
    const float* p = pool + (size_t)g * 64;
#pragma unroll 8
    for (int ci = 0; ci < 64; ++ci) s = fmaf(p[ci] / c, lin1W[ci * 32 + lane], s);
    r = fmaxf(s, 0.0f) * lin2W[lane];
  }
  for (int off = 32; off > 0; off >>= 1) r += __shfl_down(r, off, 64);
  if (lane == 0) out[g] = r + lin2b[0];
}

extern "C" void kernel_launch(void* const* d_in, const int* in_sizes, int n_in,
                              void* d_out, int out_size, void* d_ws, size_t ws_size,
                              hipStream_t stream) {
  const float* x     = (const float*)d_in[0];
  const int*   src   = (const int*)d_in[1];            // e_idx[0]
  const int*   dst   = ((const int*)d_in[1]) + NE;     // e_idx[1]
  const int*   b     = (const int*)d_in[2];
  const float* w0    = (const float*)d_in[3];
  const float* b0    = (const float*)d_in[4];
  const float* convW = (const float*)d_in[5];
  const float* convB = (const float*)d_in[6];
  const float* skipW = (const float*)d_in[7];
  const float* skipB = (const float*)d_in[8];
  const float* lin1W = (const float*)d_in[9];
  const float* lin1b = (const float*)d_in[10];
  const float* lin2W = (const float*)d_in[11];
  const float* lin2b = (const float*)d_in[12];
  float* out = (float*)d_out;

  // ---- workspace layout ----
  char* w = (char*)d_ws;
  const size_t NPAD = 102400;
  int*   cnt     = (int*)w;                  w += NPAD * 4;
  float* dinv    = (float*)w;                w += NPAD * 4;
  int*   row_ptr = (int*)w;                  w += NPAD * 4;
  int*   bcur    = (int*)w;                  w += 1024 * 4;
  u64*   ebuf    = (u64*)w;                  w += (size_t)NBK * CAP * 8;  // 16.8MB
  int*   csr_src = (int*)w;                  w += (size_t)NBK * CAP * 4 + 1024;
  float* hA      = (float*)w;                w += (size_t)NN * 64 * 4;
  float* hS      = (float*)w;                w += (size_t)NN * 64 * 4;
  float* pool    = (float*)w;                w += (size_t)NG * 64 * 4;
  float* pcnt    = (float*)w;                w += (size_t)NG * 4;
  // hw16 (12.8MB) reuses ebuf (16.8MB): ebuf consumed by k_csr before gemm0.
  u32* hw16 = (u32*)ebuf;

  // ---- CSR build: block-local bucket sort (once per launch) ----
  hipMemsetAsync(bcur, 0, NBK * sizeof(int), stream);
  k_bin<<<NBLK_BIN, 256, 0, stream>>>(src, dst, bcur, ebuf);
  k_csr<<<NBK, 256, 0, stream>>>(bcur, ebuf, row_ptr, cnt, dinv, csr_src);

  const int GT = (NN + 255) / 256;  // 391 tiles

  // ---- layer 0 ----
  k_gemm<NF, false><<<GT, 256, 0, stream>>>(x, w0, nullptr, nullptr, dinv,
                                            hw16, nullptr);
  k_agg<false><<<12500, 256, 0, stream>>>(hw16, nullptr, csr_src, row_ptr, cnt,
                                          dinv, b0, hA);
  // ---- layers 1..2 ----
  for (int i = 0; i < 2; ++i) {
    k_gemm<H, true><<<GT, 256, 0, stream>>>(hA, convW + (size_t)i * H * H,
                                            skipW + (size_t)i * H * H,
                                            skipB + (size_t)i * H, dinv, hw16, hS);
    k_agg<true><<<12500, 256, 0, stream>>>(hw16, hS, csr_src, row_ptr, cnt,
                                           dinv, convB + (size_t)i * H, hA);
  }

  // ---- mean pool + head ----
  hipMemsetAsync(pool, 0, ((size_t)NG * 64 + NG) * sizeof(float), stream);
  k_pool<<<(NN / 256) + 1, 256, 0, stream>>>(hA, b, pool, pcnt);
  k_head<<<NG, 64, 0, stream>>>(pool, pcnt, lin1W, lin1b, lin2W, lin2b, out);
}

// Round 10
// 330.229 us; speedup vs baseline: 1.9362x; 1.1098x over previous
//
#include <hip/hip_runtime.h>
#include <hip/hip_fp16.h>

#define NN 100000      // nodes
#define NE 1600000     // edges
#define NF 128         // input features
#define H  64          // hidden channels
#define NG 4096        // graphs

#define NBK 512        // dst buckets
#define BKN 196        // nodes per bucket (512*196 >= NN)
#define CAP 4096       // edge capacity per bucket (avg 3125, sigma 56)
#define NBLK_BIN 256
#define CHUNK ((NE + NBLK_BIN - 1) / NBLK_BIN)   // 6250

typedef unsigned long long u64;
typedef unsigned int u32;

__device__ inline u32 packh2(float x, float y) {
  __half2 h = __floats2half2_rn(x, y);
  return *reinterpret_cast<u32*>(&h);
}
__device__ inline float2 unpackh2(u32 u) {
  __half2 h = *reinterpret_cast<__half2*>(&u);
  return __half22float2(h);
}

// ---- phase 1: bucket-bin edges (u32 = dloc<<17 | src), block-local runs ----
__global__ __launch_bounds__(256) void k_bin(const int* __restrict__ src,
                                             const int* __restrict__ dst,
                                             int* __restrict__ bcur,
                                             u32* __restrict__ ebuf) {
  __shared__ int d_s[CHUNK];          // 25 KB: dst chunk staged once
  __shared__ int bcnt[NBK], bpos[NBK];
  const int e0 = blockIdx.x * CHUNK;
  const int e1 = min(e0 + CHUNK, NE);
  for (int i = threadIdx.x; i < NBK; i += 256) bcnt[i] = 0;
  __syncthreads();
  for (int e = e0 + threadIdx.x; e < e1; e += 256) {
    const int d = dst[e];
    d_s[e - e0] = d;
    atomicAdd(&bcnt[d / BKN], 1);
  }
  __syncthreads();
  for (int i = threadIdx.x; i < NBK; i += 256) {
    const int c = bcnt[i];
    if (c) bpos[i] = i * CAP + atomicAdd(&bcur[i], c);
  }
  __syncthreads();
  for (int e = e0 + threadIdx.x; e < e1; e += 256) {
    const int d = d_s[e - e0];
    const int bk = d / BKN;
    const int pos = atomicAdd(&bpos[bk], 1);
    ebuf[pos] = ((u32)(d - bk * BKN) << 17) | (u32)src[e];
  }
}

// ---- phase 2: per-bucket CSR build, src-octant-ordered adjacency ----------
// One block per bucket. Edges staged in LDS; 8 octant passes make each
// node's list sorted by src>>14 -> k_agg gathers get L2 phase-locality.
__global__ __launch_bounds__(256) void k_csr(const int* __restrict__ bcur,
                                             const u32* __restrict__ ebuf,
                                             int* __restrict__ row_ptr,
                                             int* __restrict__ cnt,
                                             float* __restrict__ dinv,
                                             int* __restrict__ csr_src) {
  __shared__ u32 eb_s[CAP];           // 16 KB
  __shared__ int deg[256], sc[256], cur[256];
  const int bk = blockIdx.x;
  const int nlo = bk * BKN;
  if (nlo >= NN) return;
  const int nloc = min(BKN, NN - nlo);
  const int cntE = bcur[bk];
  const int t = threadIdx.x;
  for (int e = t; e < cntE; e += 256) eb_s[e] = ebuf[(size_t)bk * CAP + e];
  deg[t] = 0;
  __syncthreads();
  for (int e = t; e < cntE; e += 256) atomicAdd(&deg[eb_s[e] >> 17], 1);
  __syncthreads();
  sc[t] = deg[t];
  __syncthreads();
  for (int off = 1; off < 256; off <<= 1) {
    const int add = (t >= off) ? sc[t - off] : 0;
    __syncthreads();
    sc[t] += add;
    __syncthreads();
  }
  const int excl = bk * CAP + sc[t] - deg[t];
  if (t < nloc) {
    row_ptr[nlo + t] = excl;
    cnt[nlo + t] = deg[t];
    dinv[nlo + t] = 1.0f / sqrtf((float)deg[t] + 1.0f);
  }
  cur[t] = excl;
  __syncthreads();
  for (int oct = 0; oct < 8; ++oct) {
    for (int e = t; e < cntE; e += 256) {
      const u32 ent = eb_s[e];
      const int s = (int)(ent & 0x1ffffu);
      if (((s >> 14) & 7) == oct) {
        const int pos = atomicAdd(&cur[ent >> 17], 1);
        csr_src[pos] = s;
      }
    }
    __syncthreads();
  }
}

// ---- node GEMM, LDS-tiled, micro-tile 8x8, k-chunk 8 ----------------------
// Block 256 threads = tile 256 rows x 64 cols. tin plane stride 388
// (388%32==4 -> staging write conflicts <=2-way; reads conflict-free).
// Epilogue scales by dinv[row], packs fp16 -> out16. SK: skip fp32 -> outS.
#define TSTR 388
template <int CI, bool SK>
__global__ __launch_bounds__(256) void k_gemm(const float* __restrict__ in,
                                              const float* __restrict__ W,
                                              const float* __restrict__ Ws,
                                              const float* __restrict__ bs,
                                              const float* __restrict__ dinv,
                                              u32* __restrict__ out16,
                                              float* __restrict__ outS) {
  __shared__ float wt[CI * 64];
  __shared__ float wsl[SK ? 64 * 64 : 1];
  __shared__ float tin[8 * TSTR];  // 12.4 KB
  for (int i = threadIdx.x; i < CI * 64; i += 256) wt[i] = W[i];
  if (SK)
    for (int i = threadIdx.x; i < 64 * 64; i += 256) wsl[i] = Ws[i];

  const int row0 = blockIdx.x * 256;
  const int rg = threadIdx.x >> 3;  // 0..31: 8-row group
  const int cg = threadIdx.x & 7;   // 0..7 : 8-col group
  float acc[8][8];
  float sacc[SK ? 8 : 1][SK ? 8 : 1];
#pragma unroll
  for (int i = 0; i < 8; ++i)
#pragma unroll
    for (int j = 0; j < 8; ++j) acc[i][j] = 0.0f;
  if (SK) {
#pragma unroll
    for (int i = 0; i < 8; ++i)
#pragma unroll
      for (int j = 0; j < 8; ++j) sacc[i][j] = bs[cg * 8 + j];
  }

  const int kk = (threadIdx.x & 1) * 4;
  const int rr = threadIdx.x >> 1;  // 0..127
  for (int k0 = 0; k0 < CI; k0 += 8) {
    __syncthreads();  // previous chunk fully consumed (also covers wt init)
#pragma unroll
    for (int s = 0; s < 2; ++s) {
      const int r = s * 128 + rr;
      const int rowc = min(row0 + r, NN - 1);
      const float4 v = *(const float4*)(in + (size_t)rowc * CI + k0 + kk);
      const int base = (r >> 3) * 12 + (r & 7);
      tin[(kk + 0) * TSTR + base] = v.x;
      tin[(kk + 1) * TSTR + base] = v.y;
      tin[(kk + 2) * TSTR + base] = v.z;
      tin[(kk + 3) * TSTR + base] = v.w;
    }
    __syncthreads();
#pragma unroll
    for (int k = 0; k < 8; ++k) {
      const float4 a0 = *(const float4*)&tin[k * TSTR + rg * 12];
      const float4 a1 = *(const float4*)&tin[k * TSTR + rg * 12 + 4];
      const float af[8] = {a0.x, a0.y, a0.z, a0.w, a1.x, a1.y, a1.z, a1.w};
      const float4 b0 = *(const float4*)&wt[(k0 + k) * 64 + cg * 8];
      const float4 b1 = *(const float4*)&wt[(k0 + k) * 64 + cg * 8 + 4];
      const float bf[8] = {b0.x, b0.y, b0.z, b0.w, b1.x, b1.y, b1.z, b1.w};
#pragma unroll
      for (int i = 0; i < 8; ++i)
#pragma unroll
        for (int j = 0; j < 8; ++j) acc[i][j] = fmaf(af[i], bf[j], acc[i][j]);
      if (SK) {
        const float4 c0 = *(const float4*)&wsl[(k0 + k) * 64 + cg * 8];
        const float4 c1 = *(const float4*)&wsl[(k0 + k) * 64 + cg * 8 + 4];
        const float cf[8] = {c0.x, c0.y, c0.z, c0.w, c1.x, c1.y, c1.z, c1.w};
#pragma unroll
        for (int i = 0; i < 8; ++i)
#pragma unroll
          for (int j = 0; j < 8; ++j) sacc[i][j] = fmaf(af[i], cf[j], sacc[i][j]);
      }
    }
  }
#pragma unroll
  for (int i = 0; i < 8; ++i) {
    const int row = row0 + rg * 8 + i;
    if (row < NN) {
      const float dv = dinv[row];
      u32 o[4];
#pragma unroll
      for (int j = 0; j < 4; ++j)
        o[j] = packh2(acc[i][2 * j] * dv, acc[i][2 * j + 1] * dv);
      *(uint4*)&out16[(size_t)row * 32 + cg * 4] =
          make_uint4(o[0], o[1], o[2], o[3]);
      if (SK) {
        float* sp = outS + (size_t)row * 64 + cg * 8;
        *(float4*)(sp) = make_float4(sacc[i][0], sacc[i][1], sacc[i][2], sacc[i][3]);
        *(float4*)(sp + 4) = make_float4(sacc[i][4], sacc[i][5], sacc[i][6], sacc[i][7]);
      }
    }
  }
}

// ------- CSR aggregation + finalize (fp16 gather) ---------------------------
// wave = 2 nodes x 32 lanes; lane owns a col PAIR (one u32 = 2 fp16).
// h = relu((sum_nbrs + self) * dinv_d + bias) [+ hs]; accumulation in fp32.
template <bool ADD_S>
__global__ __launch_bounds__(256) void k_agg(const u32* __restrict__ hw16,
                                             const float* __restrict__ hs,
                                             const int* __restrict__ csr_src,
                                             const int* __restrict__ row_ptr,
                                             const int* __restrict__ cnt,
                                             const float* __restrict__ dinv,
                                             const float* __restrict__ bias,
                                             float* __restrict__ h) {
  const int lane = threadIdx.x & 31;        // col-pair index
  const int half = (threadIdx.x >> 5) & 1;  // node within pair
  const int wv = threadIdx.x >> 6;          // wave 0..3
  const int n = (blockIdx.x * 4 + wv) * 2 + half;  // NN = 12500*8 exactly
  const int beg = row_ptr[n];
  const int deg = cnt[n];
  const int dm = max(deg, __shfl_xor(deg, 32));
  float2 a[8];
#pragma unroll
  for (int k = 0; k < 8; ++k) a[k] = make_float2(0.0f, 0.0f);
  int i = 0;

#define GSTEP(NK)                                                             \
  {                                                                           \
    int p[NK];                                                                \
    u32 uv[NK];                                                               \
    _Pragma("unroll") for (int k = 0; k < NK; ++k) {                          \
      int e = i + k;                                                          \
      e = e < deg ? e : deg - 1;                                              \
      e = e > 0 ? e : 0;                                                      \
      p[k] = __builtin_nontemporal_load(&csr_src[beg + e]);                   \
    }                                                                         \
    _Pragma("unroll") for (int k = 0; k < NK; ++k)                            \
        uv[k] = hw16[(size_t)p[k] * 32 + lane];                               \
    _Pragma("unroll") for (int k = 0; k < NK; ++k) {                          \
      const float2 f = unpackh2(uv[k]);                                       \
      const bool ok = (i + k) < deg;                                          \
      a[k & 7].x += ok ? f.x : 0.0f;                                          \
      a[k & 7].y += ok ? f.y : 0.0f;                                          \
    }                                                                         \
    i += NK;                                                                  \
  }

  while (i + 16 <= dm) GSTEP(16)
  if (i + 8 <= dm) GSTEP(8)
  if (i + 4 <= dm) GSTEP(4)
  if (i + 2 <= dm) GSTEP(2)
  if (i < dm) GSTEP(1)
#undef GSTEP

  float2 t0 = make_float2(a[0].x + a[1].x, a[0].y + a[1].y);
  float2 t1 = make_float2(a[2].x + a[3].x, a[2].y + a[3].y);
  float2 t2 = make_float2(a[4].x + a[5].x, a[4].y + a[5].y);
  float2 t3 = make_float2(a[6].x + a[7].x, a[6].y + a[7].y);
  float2 acc = make_float2((t0.x + t1.x) + (t2.x + t3.x),
                           (t0.y + t1.y) + (t2.y + t3.y));
  const float2 self = unpackh2(hw16[(size_t)n * 32 + lane]);
  const float dv = dinv[n];
  const float2 brc = *(const float2*)&bias[2 * lane];
  float2 r;
  r.x = fmaxf((acc.x + self.x) * dv + brc.x, 0.0f);
  r.y = fmaxf((acc.y + self.y) * dv + brc.y, 0.0f);
  if (ADD_S) {
    const float2 s = *(const float2*)&hs[(size_t)n * 64 + 2 * lane];
    r.x += s.x;
    r.y += s.y;
  }
  *(float2*)&h[(size_t)n * 64 + 2 * lane] = r;
}

// -------- mean-pool: b is SORTED -> run-length accumulate, few atomics ------
__global__ __launch_bounds__(256) void k_pool(const float* __restrict__ h,
                                              const int* __restrict__ b,
                                              float* __restrict__ pool,
                                              float* __restrict__ cnt) {
  const int col = threadIdx.x & 63;
  const int wv  = threadIdx.x >> 6;
  const int node0 = (blockIdx.x * 4 + wv) * 64;
  if (node0 >= NN) return;
  const int node1 = min(node0 + 64, NN);
  int gcur = b[node0];
  float acc = 0.f;
  float run = 0.f;
  for (int n = node0; n < node1; ++n) {
    const int g = b[n];  // wave-uniform broadcast load
    if (g != gcur) {
      atomicAdd(&pool[(size_t)gcur * 64 + col], acc);
      if (col == 0) atomicAdd(&cnt[gcur], run);
      gcur = g; acc = 0.f; run = 0.f;
    }
    acc += h[(size_t)n * 64 + col];
    run += 1.f;
  }
  atomicAdd(&pool[(size_t)gcur * 64 + col], acc);
  if (col == 0) atomicAdd(&cnt[gcur], run);
}

// ---------------- MLP head ----------------
__global__ __launch_bounds__(64) void k_head(const float* __restrict__ pool,
                                             const float* __restrict__ cnt,
                                             const float* __restrict__ lin1W,
                                             const float* __restrict__ lin1b,
                                             const float* __restrict__ lin2W,
                                             const float* __restrict__ lin2b,
                                             float* __restrict__ out) {
  const int g = blockIdx.x;
  const int lane = threadIdx.x;
  const float c = fmaxf(cnt[g], 1.0f);
  float r = 0.f;
  if (lane < 32) {
    float s = lin1b[lane];
    const float* p = pool + (size_t)g * 64;
#pragma unroll 8
    for (int ci = 0; ci < 64; ++ci) s = fmaf(p[ci] / c, lin1W[ci * 32 + lane], s);
    r = fmaxf(s, 0.0f) * lin2W[lane];
  }
  for (int off = 32; off > 0; off >>= 1) r += __shfl_down(r, off, 64);
  if (lane == 0) out[g] = r + lin2b[0];
}

extern "C" void kernel_launch(void* const* d_in, const int* in_sizes, int n_in,
                              void* d_out, int out_size, void* d_ws, size_t ws_size,
                              hipStream_t stream) {
  const float* x     = (const float*)d_in[0];
  const int*   src   = (const int*)d_in[1];            // e_idx[0]
  const int*   dst   = ((const int*)d_in[1]) + NE;     // e_idx[1]
  const int*   b     = (const int*)d_in[2];
  const float* w0    = (const float*)d_in[3];
  const float* b0    = (const float*)d_in[4];
  const float* convW = (const float*)d_in[5];
  const float* convB = (const float*)d_in[6];
  const float* skipW = (const float*)d_in[7];
  const float* skipB = (const float*)d_in[8];
  const float* lin1W = (const float*)d_in[9];
  const float* lin1b = (const float*)d_in[10];
  const float* lin2W = (const float*)d_in[11];
  const float* lin2b = (const float*)d_in[12];
  float* out = (float*)d_out;

  // ---- workspace layout ----
  char* w = (char*)d_ws;
  const size_t NPAD = 102400;
  int*   cnt     = (int*)w;                  w += NPAD * 4;
  float* dinv    = (float*)w;                w += NPAD * 4;
  int*   row_ptr = (int*)w;                  w += NPAD * 4;
  int*   bcur    = (int*)w;                  w += 1024 * 4;
  int*   csr_src = (int*)w;                  w += (size_t)NBK * CAP * 4;   // 8.4MB
  char*  big     = w;                        w += (size_t)NN * 32 * 4;     // 12.8MB
  float* hA      = (float*)w;                w += (size_t)NN * 64 * 4;
  float* hS      = (float*)w;                w += (size_t)NN * 64 * 4;
  float* pool    = (float*)w;                w += (size_t)NG * 64 * 4;
  float* pcnt    = (float*)w;                w += (size_t)NG * 4;
  // ebuf (8.4MB, dead after k_csr) and hw16 (12.8MB) share `big`.
  u32* ebuf = (u32*)big;
  u32* hw16 = (u32*)big;

  // ---- CSR build: block-local bucket sort, octant-ordered (once/launch) ----
  hipMemsetAsync(bcur, 0, NBK * sizeof(int), stream);
  k_bin<<<NBLK_BIN, 256, 0, stream>>>(src, dst, bcur, ebuf);
  k_csr<<<NBK, 256, 0, stream>>>(bcur, ebuf, row_ptr, cnt, dinv, csr_src);

  const int GT = (NN + 255) / 256;  // 391 tiles

  // ---- layer 0 ----
  k_gemm<NF, false><<<GT, 256, 0, stream>>>(x, w0, nullptr, nullptr, dinv,
                                            hw16, nullptr);
  k_agg<false><<<12500, 256, 0, stream>>>(hw16, nullptr, csr_src, row_ptr, cnt,
                                          dinv, b0, hA);
  // ---- layers 1..2 ----
  for (int i = 0; i < 2; ++i) {
    k_gemm<H, true><<<GT, 256, 0, stream>>>(hA, convW + (size_t)i * H * H,
                                            skipW + (size_t)i * H * H,
                                            skipB + (size_t)i * H, dinv, hw16, hS);
    k_agg<true><<<12500, 256, 0, stream>>>(hw16, hS, csr_src, row_ptr, cnt,
                                           dinv, convB + (size_t)i * H, hA);
  }

  // ---- mean pool + head ----
  hipMemsetAsync(pool, 0, ((size_t)NG * 64 + NG) * sizeof(float), stream);
  k_pool<<<(NN / 256) + 1, 256, 0, stream>>>(hA, b, pool, pcnt);
  k_head<<<NG, 64, 0, stream>>>(pool, pcnt, lin1W, lin1b, lin2W, lin2b, out);
}

// Round 11
// 323.322 us; speedup vs baseline: 1.9775x; 1.0214x over previous
//
#include <hip/hip_runtime.h>
#include <hip/hip_fp16.h>

#define NN 100000      // nodes
#define NE 1600000     // edges
#define NF 128         // input features
#define H  64          // hidden channels
#define NG 4096        // graphs

#define NBK 512        // dst buckets
#define BKN 196        // nodes per bucket (512*196 >= NN)
#define CAP 4096       // edge capacity per bucket (avg 3125, sigma 56)
#define NBLK_BIN 256
#define CHUNK ((NE + NBLK_BIN - 1) / NBLK_BIN)   // 6250

typedef unsigned long long u64;
typedef unsigned int u32;

__device__ inline u32 packh2(float x, float y) {
  __half2 h = __floats2half2_rn(x, y);
  return *reinterpret_cast<u32*>(&h);
}
__device__ inline float2 unpackh2(u32 u) {
  __half2 h = *reinterpret_cast<__half2*>(&u);
  return __half22float2(h);
}

// ---- phase 1: bucket-bin edges (u32 = dloc<<17 | src), block-local runs ----
__global__ __launch_bounds__(256) void k_bin(const int* __restrict__ src,
                                             const int* __restrict__ dst,
                                             int* __restrict__ bcur,
                                             u32* __restrict__ ebuf) {
  __shared__ int d_s[CHUNK];          // 25 KB: dst chunk staged once
  __shared__ int bcnt[NBK], bpos[NBK];
  const int e0 = blockIdx.x * CHUNK;
  const int e1 = min(e0 + CHUNK, NE);
  for (int i = threadIdx.x; i < NBK; i += 256) bcnt[i] = 0;
  __syncthreads();
  for (int e = e0 + threadIdx.x; e < e1; e += 256) {
    const int d = dst[e];
    d_s[e - e0] = d;
    atomicAdd(&bcnt[d / BKN], 1);
  }
  __syncthreads();
  for (int i = threadIdx.x; i < NBK; i += 256) {
    const int c = bcnt[i];
    if (c) bpos[i] = i * CAP + atomicAdd(&bcur[i], c);
  }
  __syncthreads();
  for (int e = e0 + threadIdx.x; e < e1; e += 256) {
    const int d = d_s[e - e0];
    const int bk = d / BKN;
    const int pos = atomicAdd(&bpos[bk], 1);
    ebuf[pos] = ((u32)(d - bk * BKN) << 17) | (u32)src[e];
  }
}

// ---- phase 2: per-bucket CSR build, src-octant-ordered adjacency ----------
// csr entries stored PRE-SCALED (src*16 = u64-row index of hw16).
// Bucket tail padded with 64 zeros so k_agg can over-read without clamping.
__global__ __launch_bounds__(256) void k_csr(const int* __restrict__ bcur,
                                             const u32* __restrict__ ebuf,
                                             int* __restrict__ row_ptr,
                                             int* __restrict__ cnt,
                                             float* __restrict__ dinv,
                                             int* __restrict__ csr_src) {
  __shared__ u32 eb_s[CAP];           // 16 KB
  __shared__ int deg[256], sc[256], cur[256];
  const int bk = blockIdx.x;
  const int nlo = bk * BKN;
  if (nlo >= NN) return;
  const int nloc = min(BKN, NN - nlo);
  const int cntE = bcur[bk];
  const int t = threadIdx.x;
  for (int e = t; e < cntE; e += 256) eb_s[e] = ebuf[(size_t)bk * CAP + e];
  deg[t] = 0;
  __syncthreads();
  for (int e = t; e < cntE; e += 256) atomicAdd(&deg[eb_s[e] >> 17], 1);
  __syncthreads();
  sc[t] = deg[t];
  __syncthreads();
  for (int off = 1; off < 256; off <<= 1) {
    const int add = (t >= off) ? sc[t - off] : 0;
    __syncthreads();
    sc[t] += add;
    __syncthreads();
  }
  const int excl = bk * CAP + sc[t] - deg[t];
  if (t < nloc) {
    row_ptr[nlo + t] = excl;
    cnt[nlo + t] = deg[t];
    dinv[nlo + t] = 1.0f / sqrtf((float)deg[t] + 1.0f);
  }
  cur[t] = excl;
  __syncthreads();
  for (int oct = 0; oct < 8; ++oct) {
    for (int e = t; e < cntE; e += 256) {
      const u32 ent = eb_s[e];
      const int s = (int)(ent & 0x1ffffu);
      if (((s >> 14) & 7) == oct) {
        const int pos = atomicAdd(&cur[ent >> 17], 1);
        csr_src[pos] = s << 4;  // pre-scaled
      }
    }
    __syncthreads();
  }
  // zero-pad tail so degree-mismatched quads can over-read safely
  for (int e = cntE + t; e < min(cntE + 64, CAP); e += 256)
    csr_src[bk * CAP + e] = 0;
}

// ---- degree counting sort: order[] groups nodes of equal/adjacent degree ---
// Pairing is numerically inert: each node's sum is over its own csr list.
__global__ __launch_bounds__(256) void k_obin(const int* __restrict__ cnt,
                                              int* __restrict__ gcur) {
  __shared__ int lh[64];
  const int t = threadIdx.x;
  if (t < 64) lh[t] = 0;
  __syncthreads();
  const int n = blockIdx.x * 256 + t;
  if (n < NN) atomicAdd(&lh[min(cnt[n], 63)], 1);
  __syncthreads();
  if (t < 64 && lh[t]) atomicAdd(&gcur[t], lh[t]);
}

__global__ __launch_bounds__(64) void k_oscan(int* __restrict__ gcur) {
  __shared__ int sh[64];
  const int t = threadIdx.x;
  const int v = gcur[t];
  sh[t] = v;
  __syncthreads();
  for (int off = 1; off < 64; off <<= 1) {
    const int a = (t >= off) ? sh[t - off] : 0;
    __syncthreads();
    sh[t] += a;
    __syncthreads();
  }
  gcur[t] = sh[t] - v;  // exclusive offset -> running cursor
}

__global__ __launch_bounds__(256) void k_oscat(const int* __restrict__ cnt,
                                               int* __restrict__ gcur,
                                               int* __restrict__ order) {
  __shared__ int lh[64], lo[64];
  const int t = threadIdx.x;
  if (t < 64) lh[t] = 0;
  __syncthreads();
  const int n = blockIdx.x * 256 + t;
  int bin = 0, loc = 0;
  if (n < NN) {
    bin = min(cnt[n], 63);
    loc = atomicAdd(&lh[bin], 1);
  }
  __syncthreads();
  if (t < 64 && lh[t]) lo[t] = atomicAdd(&gcur[t], lh[t]);
  __syncthreads();
  if (n < NN) order[lo[bin] + loc] = n;
}

// ---- node GEMM, LDS-tiled, micro-tile 8x8, k-chunk 8 ----------------------
#define TSTR 388
template <int CI, bool SK>
__global__ __launch_bounds__(256) void k_gemm(const float* __restrict__ in,
                                              const float* __restrict__ W,
                                              const float* __restrict__ Ws,
                                              const float* __restrict__ bs,
                                              const float* __restrict__ dinv,
                                              u32* __restrict__ out16,
                                              float* __restrict__ outS) {
  __shared__ float wt[CI * 64];
  __shared__ float wsl[SK ? 64 * 64 : 1];
  __shared__ float tin[8 * TSTR];  // 12.4 KB
  for (int i = threadIdx.x; i < CI * 64; i += 256) wt[i] = W[i];
  if (SK)
    for (int i = threadIdx.x; i < 64 * 64; i += 256) wsl[i] = Ws[i];

  const int row0 = blockIdx.x * 256;
  const int rg = threadIdx.x >> 3;  // 0..31: 8-row group
  const int cg = threadIdx.x & 7;   // 0..7 : 8-col group
  float acc[8][8];
  float sacc[SK ? 8 : 1][SK ? 8 : 1];
#pragma unroll
  for (int i = 0; i < 8; ++i)
#pragma unroll
    for (int j = 0; j < 8; ++j) acc[i][j] = 0.0f;
  if (SK) {
#pragma unroll
    for (int i = 0; i < 8; ++i)
#pragma unroll
      for (int j = 0; j < 8; ++j) sacc[i][j] = bs[cg * 8 + j];
  }

  const int kk = (threadIdx.x & 1) * 4;
  const int rr = threadIdx.x >> 1;  // 0..127
  for (int k0 = 0; k0 < CI; k0 += 8) {
    __syncthreads();
#pragma unroll
    for (int s = 0; s < 2; ++s) {
      const int r = s * 128 + rr;
      const int rowc = min(row0 + r, NN - 1);
      const float4 v = *(const float4*)(in + (size_t)rowc * CI + k0 + kk);
      const int base = (r >> 3) * 12 + (r & 7);
      tin[(kk + 0) * TSTR + base] = v.x;
      tin[(kk + 1) * TSTR + base] = v.y;
      tin[(kk + 2) * TSTR + base] = v.z;
      tin[(kk + 3) * TSTR + base] = v.w;
    }
    __syncthreads();
#pragma unroll
    for (int k = 0; k < 8; ++k) {
      const float4 a0 = *(const float4*)&tin[k * TSTR + rg * 12];
      const float4 a1 = *(const float4*)&tin[k * TSTR + rg * 12 + 4];
      const float af[8] = {a0.x, a0.y, a0.z, a0.w, a1.x, a1.y, a1.z, a1.w};
      const float4 b0 = *(const float4*)&wt[(k0 + k) * 64 + cg * 8];
      const float4 b1 = *(const float4*)&wt[(k0 + k) * 64 + cg * 8 + 4];
      const float bf[8] = {b0.x, b0.y, b0.z, b0.w, b1.x, b1.y, b1.z, b1.w};
#pragma unroll
      for (int i = 0; i < 8; ++i)
#pragma unroll
        for (int j = 0; j < 8; ++j) acc[i][j] = fmaf(af[i], bf[j], acc[i][j]);
      if (SK) {
        const float4 c0 = *(const float4*)&wsl[(k0 + k) * 64 + cg * 8];
        const float4 c1 = *(const float4*)&wsl[(k0 + k) * 64 + cg * 8 + 4];
        const float cf[8] = {c0.x, c0.y, c0.z, c0.w, c1.x, c1.y, c1.z, c1.w};
#pragma unroll
        for (int i = 0; i < 8; ++i)
#pragma unroll
          for (int j = 0; j < 8; ++j) sacc[i][j] = fmaf(af[i], cf[j], sacc[i][j]);
      }
    }
  }
#pragma unroll
  for (int i = 0; i < 8; ++i) {
    const int row = row0 + rg * 8 + i;
    if (row < NN) {
      const float dv = dinv[row];
      u32 o[4];
#pragma unroll
      for (int j = 0; j < 4; ++j)
        o[j] = packh2(acc[i][2 * j] * dv, acc[i][2 * j + 1] * dv);
      *(uint4*)&out16[(size_t)row * 32 + cg * 4] =
          make_uint4(o[0], o[1], o[2], o[3]);
      if (SK) {
        float* sp = outS + (size_t)row * 64 + cg * 8;
        *(float4*)(sp) = make_float4(sacc[i][0], sacc[i][1], sacc[i][2], sacc[i][3]);
        *(float4*)(sp + 4) = make_float4(sacc[i][4], sacc[i][5], sacc[i][6], sacc[i][7]);
      }
    }
  }
}

// ------- CSR aggregation + finalize (fp16 gather, 4 nodes/wave) -------------
// Wave = 4 nodes x 16 lanes; lane owns a col QUAD (u64 = 4 fp16).
// Nodes come from degree-sorted order[] -> quad degrees nearly equal.
// csr pre-scaled (src*16); bucket-tail zero-padded -> no index clamping;
// out-of-degree slots masked by one cndmask->fmaf multiplier.
template <bool ADD_S>
__global__ __launch_bounds__(256) void k_agg(const u32* __restrict__ hw16,
                                             const float* __restrict__ hs,
                                             const int* __restrict__ csr_src,
                                             const int* __restrict__ row_ptr,
                                             const int* __restrict__ cnt,
                                             const float* __restrict__ dinv,
                                             const float* __restrict__ bias,
                                             const int* __restrict__ order,
                                             float* __restrict__ h) {
  const int lane = threadIdx.x & 63;
  const int grp  = lane >> 4;        // node within quad
  const int cl   = lane & 15;        // col-quad index (4 fp16 = 8 B)
  const int wv   = threadIdx.x >> 6;
  const int slot = (blockIdx.x * 4 + wv) * 4 + grp;  // NN = 6250*16 exactly
  const int n = order[slot];
  const int beg = row_ptr[n];
  const int deg = cnt[n];
  const int d1 = max(deg, __shfl_xor(deg, 16));
  const int dmax = max(d1, __shfl_xor(d1, 32));
  const u64* hw64 = (const u64*)hw16;
  float4 acc = make_float4(0.f, 0.f, 0.f, 0.f);
  int i = 0;

#define GSTEP(NK)                                                             \
  {                                                                           \
    int p[NK];                                                                \
    uint2 uv[NK];                                                             \
    _Pragma("unroll") for (int k = 0; k < NK; ++k)                            \
        p[k] = __builtin_nontemporal_load(&csr_src[beg + i + k]);             \
    _Pragma("unroll") for (int k = 0; k < NK; ++k)                            \
        uv[k] = *(const uint2*)&hw64[(size_t)(p[k] + cl)];                    \
    _Pragma("unroll") for (int k = 0; k < NK; ++k) {                          \
      const float m = ((i + k) < deg) ? 1.0f : 0.0f;                          \
      const float2 f0 = unpackh2(uv[k].x);                                    \
      const float2 f1 = unpackh2(uv[k].y);                                    \
      acc.x = fmaf(f0.x, m, acc.x);                                           \
      acc.y = fmaf(f0.y, m, acc.y);                                           \
      acc.z = fmaf(f1.x, m, acc.z);                                           \
      acc.w = fmaf(f1.y, m, acc.w);                                           \
    }                                                                         \
    i += NK;                                                                  \
  }

  while (i + 8 <= dmax) GSTEP(8)
  if (i + 4 <= dmax) GSTEP(4)
  if (i + 2 <= dmax) GSTEP(2)
  if (i < dmax) GSTEP(1)
#undef GSTEP

  const uint2 sv = *(const uint2*)&hw64[(size_t)n * 16 + cl];
  const float2 s0 = unpackh2(sv.x);
  const float2 s1 = unpackh2(sv.y);
  const float dv = dinv[n];
  const float4 brc = *(const float4*)&bias[cl * 4];
  float4 r;
  r.x = fmaxf((acc.x + s0.x) * dv + brc.x, 0.0f);
  r.y = fmaxf((acc.y + s0.y) * dv + brc.y, 0.0f);
  r.z = fmaxf((acc.z + s1.x) * dv + brc.z, 0.0f);
  r.w = fmaxf((acc.w + s1.y) * dv + brc.w, 0.0f);
  if (ADD_S) {
    const float4 s = *(const float4*)&hs[(size_t)n * 64 + cl * 4];
    r.x += s.x; r.y += s.y; r.z += s.z; r.w += s.w;
  }
  *(float4*)&h[(size_t)n * 64 + cl * 4] = r;
}

// -------- mean-pool: b is SORTED -> run-length accumulate, few atomics ------
__global__ __launch_bounds__(256) void k_pool(const float* __restrict__ h,
                                              const int* __restrict__ b,
                                              float* __restrict__ pool,
                                              float* __restrict__ cnt) {
  const int col = threadIdx.x & 63;
  const int wv  = threadIdx.x >> 6;
  const int node0 = (blockIdx.x * 4 + wv) * 64;
  if (node0 >= NN) return;
  const int node1 = min(node0 + 64, NN);
  int gcur = b[node0];
  float acc = 0.f;
  float run = 0.f;
  for (int n = node0; n < node1; ++n) {
    const int g = b[n];  // wave-uniform broadcast load
    if (g != gcur) {
      atomicAdd(&pool[(size_t)gcur * 64 + col], acc);
      if (col == 0) atomicAdd(&cnt[gcur], run);
      gcur = g; acc = 0.f; run = 0.f;
    }
    acc += h[(size_t)n * 64 + col];
    run += 1.f;
  }
  atomicAdd(&pool[(size_t)gcur * 64 + col], acc);
  if (col == 0) atomicAdd(&cnt[gcur], run);
}

// ---------------- MLP head ----------------
__global__ __launch_bounds__(64) void k_head(const float* __restrict__ pool,
                                             const float* __restrict__ cnt,
                                             const float* __restrict__ lin1W,
                                             const float* __restrict__ lin1b,
                                             const float* __restrict__ lin2W,
                                             const float* __restrict__ lin2b,
                                             float* __restrict__ out) {
  const int g = blockIdx.x;
  const int lane = threadIdx.x;
  const float c = fmaxf(cnt[g], 1.0f);
  float r = 0.f;
  if (lane < 32) {
    float s = lin1b[lane];
    const float* p = pool + (size_t)g * 64;
#pragma unroll 8
    for (int ci = 0; ci < 64; ++ci) s = fmaf(p[ci] / c, lin1W[ci * 32 + lane], s);
    r = fmaxf(s, 0.0f) * lin2W[lane];
  }
  for (int off = 32; off > 0; off >>= 1) r += __shfl_down(r, off, 64);
  if (lane == 0) out[g] = r + lin2b[0];
}

extern "C" void kernel_launch(void* const* d_in, const int* in_sizes, int n_in,
                              void* d_out, int out_size, void* d_ws, size_t ws_size,
                              hipStream_t stream) {
  const float* x     = (const float*)d_in[0];
  const int*   src   = (const int*)d_in[1];            // e_idx[0]
  const int*   dst   = ((const int*)d_in[1]) + NE;     // e_idx[1]
  const int*   b     = (const int*)d_in[2];
  const float* w0    = (const float*)d_in[3];
  const float* b0    = (const float*)d_in[4];
  const float* convW = (const float*)d_in[5];
  const float* convB = (const float*)d_in[6];
  const float* skipW = (const float*)d_in[7];
  const float* skipB = (const float*)d_in[8];
  const float* lin1W = (const float*)d_in[9];
  const float* lin1b = (const float*)d_in[10];
  const float* lin2W = (const float*)d_in[11];
  const float* lin2b = (const float*)d_in[12];
  float* out = (float*)d_out;

  // ---- workspace layout ----
  char* w = (char*)d_ws;
  const size_t NPAD = 102400;
  int*   cnt     = (int*)w;                  w += NPAD * 4;
  float* dinv    = (float*)w;                w += NPAD * 4;
  int*   row_ptr = (int*)w;                  w += NPAD * 4;
  int*   order   = (int*)w;                  w += NPAD * 4;
  int*   bcur    = (int*)w;                  w += 1024 * 4;
  int*   gcur    = (int*)w;                  w += 1024 * 4;
  int*   csr_src = (int*)w;                  w += (size_t)NBK * CAP * 4 + 4096;
  char*  big     = w;                        w += (size_t)NN * 32 * 4;     // 12.8MB
  float* hA      = (float*)w;                w += (size_t)NN * 64 * 4;
  float* hS      = (float*)w;                w += (size_t)NN * 64 * 4;
  float* pool    = (float*)w;                w += (size_t)NG * 64 * 4;
  float* pcnt    = (float*)w;                w += (size_t)NG * 4;
  // ebuf (8.4MB, dead after k_csr) and hw16 (12.8MB) share `big`.
  u32* ebuf = (u32*)big;
  u32* hw16 = (u32*)big;

  // ---- CSR build: bucket sort, octant-ordered, pre-scaled (once/launch) ----
  hipMemsetAsync(bcur, 0, NBK * sizeof(int), stream);
  hipMemsetAsync(gcur, 0, 64 * sizeof(int), stream);
  k_bin<<<NBLK_BIN, 256, 0, stream>>>(src, dst, bcur, ebuf);
  k_csr<<<NBK, 256, 0, stream>>>(bcur, ebuf, row_ptr, cnt, dinv, csr_src);
  // degree counting sort -> order[]
  const int OB = (NN + 255) / 256;  // 391
  k_obin<<<OB, 256, 0, stream>>>(cnt, gcur);
  k_oscan<<<1, 64, 0, stream>>>(gcur);
  k_oscat<<<OB, 256, 0, stream>>>(cnt, gcur, order);

  const int GT = (NN + 255) / 256;  // 391 tiles

  // ---- layer 0 ----
  k_gemm<NF, false><<<GT, 256, 0, stream>>>(x, w0, nullptr, nullptr, dinv,
                                            hw16, nullptr);
  k_agg<false><<<6250, 256, 0, stream>>>(hw16, nullptr, csr_src, row_ptr, cnt,
                                         dinv, b0, order, hA);
  // ---- layers 1..2 ----
  for (int i = 0; i < 2; ++i) {
    k_gemm<H, true><<<GT, 256, 0, stream>>>(hA, convW + (size_t)i * H * H,
                                            skipW + (size_t)i * H * H,
                                            skipB + (size_t)i * H, dinv, hw16, hS);
    k_agg<true><<<6250, 256, 0, stream>>>(hw16, hS, csr_src, row_ptr, cnt,
                                          dinv, convB + (size_t)i * H, order, hA);
  }

  // ---- mean pool + head ----
  hipMemsetAsync(pool, 0, ((size_t)NG * 64 + NG) * sizeof(float), stream);
  k_pool<<<(NN / 256) + 1, 256, 0, stream>>>(hA, b, pool, pcnt);
  k_head<<<NG, 64, 0, stream>>>(pool, pcnt, lin1W, lin1b, lin2W, lin2b, out);
}